// Round 11
// baseline (18805.017 us; speedup 1.0000x reference)
//
#include <hip/hip_runtime.h>
#include <math.h>

// Problem constants
#define BATCH  256
#define SEQT   256
#define FEATD  256
#define NHEADS 8
#define HD     32
#define HID    512
#define GATES  2048
#define BH     (BATCH*HID)       // FLOATS per h plane (2 parity slabs of BH halves)
#define TOUT   (SEQT-1)
#define NBLK   512
#define THR    1024
#define DEPTH  5                 // prefetch depth (slices)

typedef __attribute__((ext_vector_type(8))) short short8;
typedef __attribute__((ext_vector_type(4))) float f32x4;
typedef unsigned short u16;

union U8 { uint4 u4; short8 s8; };

__device__ __forceinline__ float sigm(float x)     { return 1.f / (1.f + __expf(-x)); }
__device__ __forceinline__ float tanhfast(float x) { return 1.f - 2.f / (1.f + __expf(2.f * x)); }

__device__ __forceinline__ u16 bf16rn(float f) {
    union { float f; unsigned u; } v; v.f = f;
    unsigned r = v.u + 0x7fffu + ((v.u >> 16) & 1u);
    return (u16)(r >> 16);
}
__device__ __forceinline__ float bf2f(u16 h) {
    union { float f; unsigned u; } v; v.u = ((unsigned)h) << 16; return v.f;
}

// ---------------------------------------------------------------------------
// Fused per-(n,h) attention (verified rounds 2-10). Output T-major CB8:
// attn[t][cb8=f/8][n][8] split bf16 hi/lo planes (65536 halves per t-slice).
// ---------------------------------------------------------------------------
__global__ __launch_bounds__(256) void k_attn(
    const float* __restrict__ x,  const float* __restrict__ wq,
    const float* __restrict__ wk, const float* __restrict__ wv,
    u16* __restrict__ attnH, u16* __restrict__ attnL)
{
    __shared__ float Ks[128][40];
    __shared__ float Vs[128][40];

    const int nb  = blockIdx.x;
    const int n   = nb >> 3, h = nb & 7;
    const int tid = threadIdx.x;
    const float* xbase = x + ((size_t)n * SEQT) * FEATD + h * HD;

    float qv[HD];
    {
        float xr[HD];
        const float4* xp = (const float4*)(xbase + (size_t)tid * FEATD);
        #pragma unroll
        for (int q4 = 0; q4 < 8; ++q4) {
            float4 v = xp[q4];
            xr[q4*4+0] = v.x; xr[q4*4+1] = v.y; xr[q4*4+2] = v.z; xr[q4*4+3] = v.w;
        }
        #pragma unroll
        for (int d = 0; d < HD; ++d) {
            float s = 0.f;
            #pragma unroll
            for (int e = 0; e < HD; ++e) s += xr[e] * wq[d*HD + e];
            qv[d] = s * 0.0625f;
        }
    }

    float o[HD];
    #pragma unroll
    for (int d = 0; d < HD; ++d) o[d] = 0.f;
    float m = -1e30f, ssum = 0.f;

    for (int tile = 0; tile < 2; ++tile) {
        const int j0 = tile * 128;
        __syncthreads();
        {
            const int r = tid & 127;
            const float* W = (tid < 128) ? wk : wv;
            float xt[HD];
            const float4* xp = (const float4*)(xbase + (size_t)(j0 + r) * FEATD);
            #pragma unroll
            for (int q4 = 0; q4 < 8; ++q4) {
                float4 v = xp[q4];
                xt[q4*4+0] = v.x; xt[q4*4+1] = v.y; xt[q4*4+2] = v.z; xt[q4*4+3] = v.w;
            }
            float outr[HD];
            #pragma unroll
            for (int d = 0; d < HD; ++d) {
                float s = 0.f;
                #pragma unroll
                for (int e = 0; e < HD; ++e) s += xt[e] * W[d*HD + e];
                outr[d] = s;
            }
            float (*dst)[40] = (tid < 128) ? Ks : Vs;
            #pragma unroll
            for (int d = 0; d < HD; ++d) dst[r][d] = outr[d];
        }
        __syncthreads();

        for (int j = 0; j < 128; ++j) {
            float e = 0.f;
            #pragma unroll
            for (int dq = 0; dq < 8; ++dq) {
                float4 kq = *(const float4*)&Ks[j][dq*4];
                e += qv[dq*4+0]*kq.x + qv[dq*4+1]*kq.y
                   + qv[dq*4+2]*kq.z + qv[dq*4+3]*kq.w;
            }
            if (e > m) {
                float sc = __expf(m - e);
                ssum *= sc;
                #pragma unroll
                for (int d = 0; d < HD; ++d) o[d] *= sc;
                m = e;
            }
            float p = __expf(e - m);
            ssum += p;
            #pragma unroll
            for (int dq = 0; dq < 8; ++dq) {
                float4 vq = *(const float4*)&Vs[j][dq*4];
                o[dq*4+0] += p * vq.x; o[dq*4+1] += p * vq.y;
                o[dq*4+2] += p * vq.z; o[dq*4+3] += p * vq.w;
            }
        }
    }

    const float inv = 1.f / ssum;
    #pragma unroll
    for (int dq = 0; dq < 8; ++dq) {
        ushort4 vh, vl;
        float v0 = o[dq*4+0]*inv, v1 = o[dq*4+1]*inv,
              v2 = o[dq*4+2]*inv, v3 = o[dq*4+3]*inv;
        u16 a0 = bf16rn(v0); vh.x = a0; vl.x = bf16rn(v0 - bf2f(a0));
        u16 a1 = bf16rn(v1); vh.y = a1; vl.y = bf16rn(v1 - bf2f(a1));
        u16 a2 = bf16rn(v2); vh.z = a2; vl.z = bf16rn(v2 - bf2f(a2));
        u16 a3 = bf16rn(v3); vh.w = a3; vl.w = bf16rn(v3 - bf2f(a3));
        const size_t a = (size_t)tid*65536
                       + (size_t)(h*4 + (dq >> 1))*2048
                       + (size_t)n*8 + (dq & 1)*4;
        *(ushort4*)(attnH + a) = vh;
        *(ushort4*)(attnL + a) = vl;
    }
}

// ---------------------------------------------------------------------------
// Wc = w_hid @ w_fc [512,256]; bc = w_hid @ b_fc + b_hid.
// Tiled: 8 rows/block (grid 64), w_hid rows LDS-staged, Wc row broadcast
// reused 8x. Summation order identical to rounds 2-10 -> bit-identical.
// ---------------------------------------------------------------------------
__global__ __launch_bounds__(256) void k_wcomb(
    const float* __restrict__ w_fc,  const float* __restrict__ b_fc,
    const float* __restrict__ w_hid, const float* __restrict__ b_hid,
    float* __restrict__ Wc, float* __restrict__ bc)
{
    __shared__ float wr[8][256];
    const int i0 = blockIdx.x * 8, tid = threadIdx.x;
    for (int e = tid; e < 8*256; e += 256)
        wr[e >> 8][e & 255] = w_hid[(size_t)(i0 + (e >> 8))*FEATD + (e & 255)];
    __syncthreads();
    const int j = tid;
    float acc[8] = {};
    for (int k = 0; k < FEATD; ++k) {
        const float wf = w_fc[(size_t)k*FEATD + j];
        #pragma unroll
        for (int i = 0; i < 8; ++i) acc[i] += wr[i][k] * wf;
    }
    #pragma unroll
    for (int i = 0; i < 8; ++i) Wc[(size_t)(i0 + i)*FEATD + j] = acc[i];
    if (tid < 8) {
        const int i = i0 + tid;
        float t = b_hid[i];
        for (int k = 0; k < FEATD; ++k) t += wr[tid][k] * b_fc[k];
        bc[i] = t;
    }
}

// ---------------------------------------------------------------------------
// Wx0 = W_ih[0] @ Wc [2048,256]; bx0 = W_ih[0] @ bc + b_ih[0] + b_hh[0].
// Tiled: 8 rows/block (grid 256). Bit-identical summation order.
// ---------------------------------------------------------------------------
__global__ __launch_bounds__(256) void k_wx0(
    const float* __restrict__ w_ih, const float* __restrict__ Wc,
    const float* __restrict__ bc,   const float* __restrict__ b_ih,
    const float* __restrict__ b_hh,
    float* __restrict__ Wx0, float* __restrict__ bx0)
{
    __shared__ float wr[8][512];
    const int i0 = blockIdx.x * 8, tid = threadIdx.x;
    for (int e = tid; e < 8*512; e += 256)
        wr[e >> 9][e & 511] = w_ih[(size_t)(i0 + (e >> 9))*HID + (e & 511)];
    __syncthreads();
    const int j = tid;
    float acc[8] = {};
    for (int k = 0; k < HID; ++k) {
        const float wc = Wc[(size_t)k*FEATD + j];
        #pragma unroll
        for (int i = 0; i < 8; ++i) acc[i] += wr[i][k] * wc;
    }
    #pragma unroll
    for (int i = 0; i < 8; ++i) Wx0[(size_t)(i0 + i)*FEATD + j] = acc[i];
    if (tid < 8) {
        const int i = i0 + tid;
        float t = b_ih[i] + b_hh[i];
        for (int k = 0; k < HID; ++k) t += wr[tid][k] * bc[k];
        bx0[i] = t;
    }
}

// ---------------------------------------------------------------------------
// Hybrid grid barrier over 512 blocks (verified structure, round 9):
// parallel flag arrive, block-0 aggregator (64 lanes x 8 flags), 1-word epoch.
// ---------------------------------------------------------------------------
__device__ __forceinline__ void hybrid_bar(int* flags, int* epoch, int step)
{
    __syncthreads();
    if (threadIdx.x == 0) {
        __threadfence();   // release: h stores to coherence point first
        __hip_atomic_store(&flags[blockIdx.x], step,
                           __ATOMIC_RELEASE, __HIP_MEMORY_SCOPE_AGENT);
    }
    if (blockIdx.x == 0 && threadIdx.x < 64) {
        const int base = (int)threadIdx.x * 8;
        for (;;) {
            bool ok = true;
            #pragma unroll
            for (int q = 0; q < 8; ++q)
                ok &= (__hip_atomic_load(&flags[base+q], __ATOMIC_RELAXED,
                                         __HIP_MEMORY_SCOPE_AGENT) >= step);
            if (__all(ok)) break;
            __builtin_amdgcn_s_sleep(2);
        }
        if (threadIdx.x == 0)
            __hip_atomic_store(epoch, step,
                               __ATOMIC_RELEASE, __HIP_MEMORY_SCOPE_AGENT);
    }
    if (threadIdx.x == 0) {
        while (__hip_atomic_load(epoch, __ATOMIC_RELAXED, __HIP_MEMORY_SCOPE_AGENT) < step)
            __builtin_amdgcn_s_sleep(2);
        __threadfence();   // acquire: invalidate stale cached h
    }
    __syncthreads();
}

// ---------------------------------------------------------------------------
struct Geo {
    const u16* wlh; const u16* wll;   // LDS weights (fragment-major)
    float* Cb;                        // LDS C bounce [256][17]
    int rowg;                         // batch row of A fragment (0..255)
    int aq;                           // k-quarter (lane>>4)
    int bbase;                        // B frag base = lane*8
    int Mtile, lr;                    // C placement
    int erow, hcl;                    // epilogue row (0..255) / h-col (0..3)
    int cg;                           // col-group 0..127
    const float* bsum;                // per-thread gate biases [4]
};

// Partial GEMM for this block's K-half. A = [s0 (NT0 slices) | s1], NT
// slices of K=32. CB8 source: elem (row,k) at (k>>3)*2048 + row*8 + (k&7).
// Result fragments -> Cb (no epilogue here).
template<int NT0, int NT>
__device__ __forceinline__ void do_partial(
    const Geo& G,
    const u16* __restrict__ s0H, const u16* __restrict__ s0L,
    const u16* __restrict__ s1H, const u16* __restrict__ s1L)
{
    uint4 pfH[DEPTH], pfL[DEPTH];

    auto ld = [&](int d, int s) {
        const u16* pH = (s < NT0) ? s0H : s1H;
        const u16* pL = (s < NT0) ? s0L : s1L;
        const int sl  = (s < NT0) ? s : s - NT0;
        const size_t a = ((size_t)(sl*4 + G.aq) << 11) + (size_t)G.rowg * 8;
        pfH[d] = *(const uint4*)(pH + a);
        pfL[d] = *(const uint4*)(pL + a);
    };

    constexpr int PR = (DEPTH < NT) ? DEPTH : NT;
    #pragma unroll
    for (int d = 0; d < PR; ++d) ld(d, d);

    f32x4 acc = {0.f, 0.f, 0.f, 0.f};
    #pragma unroll
    for (int s = 0; s < NT; ++s) {
        U8 ua, ul;
        ua.u4 = pfH[s % DEPTH];
        ul.u4 = pfL[s % DEPTH];
        if (s + DEPTH < NT) ld(s % DEPTH, s + DEPTH);
        const short8 bh = *(const short8*)(G.wlh + G.bbase + s*512);
        const short8 bl = *(const short8*)(G.wll + G.bbase + s*512);
        acc = __builtin_amdgcn_mfma_f32_16x16x32_bf16(ua.s8, bh, acc, 0,0,0);
        acc = __builtin_amdgcn_mfma_f32_16x16x32_bf16(ul.s8, bh, acc, 0,0,0);
        acc = __builtin_amdgcn_mfma_f32_16x16x32_bf16(ua.s8, bl, acc, 0,0,0);
    }

    const int crow = G.Mtile*16 + G.aq*4;
    #pragma unroll
    for (int r = 0; r < 4; ++r)
        G.Cb[(crow + r)*17 + G.lr] = acc[r];
}

// ---------------------------------------------------------------------------
// Persistent MFMA LSTM, split-K pairs. 512 blocks x 1024 threads
// (2 blocks/CU -> 32 waves/CU = 8/SIMD). Layer1: blocks 0..255; layer0:
// 256..511. Within layer: kh = K-half (0=A publishes partial, 1=B combines
// + epilogue); cg 0..127 owns 16 gate-cols (4 h-cols) x 256 rows.
// Block index remap keeps h-line-sharing cg pairs on the same XCD.
// Weights split-bf16 LDS (fragment-major, conflict-free). Hybrid barrier.
// ---------------------------------------------------------------------------
__global__ __launch_bounds__(THR, 8) void k_lstm(
    const u16* __restrict__ attnH, const u16* __restrict__ attnL,
    const float* __restrict__ Wx0, const float* __restrict__ bx0,
    u16* __restrict__ h0h, u16* __restrict__ h0l,
    u16* __restrict__ h1h, u16* __restrict__ h1l,
    const float* __restrict__ w_ih, const float* __restrict__ w_hh,
    const float* __restrict__ b_ih, const float* __restrict__ b_hh,
    const float* __restrict__ w_out, const float* __restrict__ b_out,
    float* __restrict__ out, int* __restrict__ flags, int* __restrict__ epoch,
    int* __restrict__ pairflag, float* __restrict__ Pbuf)
{
    extern __shared__ char smem[];
    const int tid  = threadIdx.x;
    const int bx   = blockIdx.x;
    const bool lay1 = (bx < 256);
    const int r256 = lay1 ? bx : bx - 256;
    const int kh   = (r256 >= 128);            // 0 = A (publish), 1 = B (finish)
    const int rr   = r256 & 127;
    const int cg   = (rr & 63)*2 + (rr >> 6);  // sharers cg,cg^1 -> bx diff 64 (same XCD)
    const int pid  = (lay1 ? 0 : 128) + cg;
    const int NSH  = lay1 ? 16 : 12;           // K-half slices
    const int KWH  = NSH * 32;

    u16*   wlh = (u16*)smem;                   // [NSH][64][8] halves (<=16KB)
    u16*   wll = wlh + 8192;
    float* Cb  = (float*)(smem + 32768);       // [256][17] f32

    const int wid = tid >> 6, l = tid & 63;
    const int lr = l & 15, aq = l >> 4;

    Geo G;
    G.wlh = wlh; G.wll = wll; G.Cb = Cb;
    G.rowg = wid*16 + lr;
    G.aq = aq;
    G.Mtile = wid; G.lr = lr;
    G.bbase = l*8;
    G.erow = tid & 255; G.hcl = tid >> 8;
    G.cg = cg;

    // ---- stage this K-half's weights: split bf16 hi/lo, fragment-major.
    // (c,kl) -> idx = (kl>>5)*512 + ((kl>>3)&3)*128 + c*8 + (kl&7)
    {
        const float* wih1 = w_ih + (size_t)GATES*HID;
        const float* whh1 = w_hh + (size_t)GATES*HID;
        for (int c = 0; c < 16; ++c) {
            const int grow = (c >> 2)*HID + cg*4 + (c & 3);
            for (int kl = tid; kl < KWH; kl += THR) {
                float f;
                if (lay1) {
                    f = (kh == 0) ? wih1[(size_t)grow*HID + kl]
                                  : whh1[(size_t)grow*HID + kl];
                } else {
                    if (kh == 0)
                        f = (kl < 256) ? Wx0[(size_t)grow*FEATD + kl]
                                       : w_hh[(size_t)grow*HID + (kl - 256)];
                    else
                        f = w_hh[(size_t)grow*HID + 128 + kl];
                }
                const u16 hi = bf16rn(f);
                const int fidx = (kl >> 5)*512 + (((kl >> 3) & 3) << 7) + c*8 + (kl & 7);
                wlh[fidx] = hi;
                wll[fidx] = bf16rn(f - bf2f(hi));
            }
        }
    }

    float bsum[4];
    #pragma unroll
    for (int g = 0; g < 4; ++g) {
        const int gidx = g*HID + cg*4 + G.hcl;
        bsum[g] = lay1 ? (b_ih[GATES + gidx] + b_hh[GATES + gidx]) : bx0[gidx];
    }
    G.bsum = bsum;
    float cr = 0.f;                    // cell state (B blocks only)
    __syncthreads();

    float* Pb = Pbuf + (size_t)pid * 4096;

    // A: publish partial (Cb -> Pbuf coalesced) + pair flag
    auto pubA = [&](int S) {
        __syncthreads();               // Cb complete
        #pragma unroll
        for (int g = 0; g < 4; ++g)
            Pb[(g*4 + G.hcl)*256 + G.erow] = Cb[G.erow*17 + g*4 + G.hcl];
        __syncthreads();               // all Pb stores drained (vmcnt0 at barrier)
        if (tid == 0) {
            __threadfence();
            __hip_atomic_store(&pairflag[pid], S,
                               __ATOMIC_RELEASE, __HIP_MEMORY_SCOPE_AGENT);
        }
    };

    // B: wait partner, combine, gates, cell update, h store
    auto finishB = [&](u16* dH, u16* dL, int S) {
        __syncthreads();               // own Cb complete
        if (tid == 0) {
            while (__hip_atomic_load(&pairflag[pid], __ATOMIC_RELAXED,
                                     __HIP_MEMORY_SCOPE_AGENT) < S)
                __builtin_amdgcn_s_sleep(2);
            __threadfence();           // acquire partner's Pbuf
        }
        __syncthreads();
        float g4[4];
        #pragma unroll
        for (int g = 0; g < 4; ++g)
            g4[g] = Cb[G.erow*17 + g*4 + G.hcl]
                  + Pb[(g*4 + G.hcl)*256 + G.erow] + bsum[g];
        const float gi = sigm(g4[0]), gf = sigm(g4[1]);
        const float gg = tanhfast(g4[2]), go = sigm(g4[3]);
        cr = gf*cr + gi*gg;
        const float h = go * tanhfast(cr);
        const u16 hh = bf16rn(h);
        const u16 hl = bf16rn(h - bf2f(hh));
        const size_t a = (size_t)(cg >> 1)*2048 + (size_t)G.erow*8
                       + (cg & 1)*4 + G.hcl;
        dH[a] = hh; dL[a] = hl;
    };

    // projection (layer-0 A blocks): rows 2cg, 2cg+1
    auto proj = [&](const u16* hH, const u16* hL, int tout) {
        if (tid < 256) {
            const int r = tid >> 7, j = (tid >> 4) & 7, ks = tid & 15;
            const int n = 2*cg + r;
            float s = 0.f;
            #pragma unroll
            for (int kk = 0; kk < 32; ++kk) {
                const int k = ks*32 + kk;
                const size_t a = (size_t)(k >> 3)*2048 + (size_t)n*8 + (k & 7);
                float hv = bf2f(hH[a]) + bf2f(hL[a]);
                hv = hv > 0.f ? hv : 0.f;
                s += hv * w_out[(size_t)j*HID + k];
            }
            s += __shfl_xor(s, 1); s += __shfl_xor(s, 2);
            s += __shfl_xor(s, 4); s += __shfl_xor(s, 8);
            if (ks == 0)
                out[(size_t)n*(TOUT*NHEADS) + (size_t)tout*NHEADS + j] = s + b_out[j];
        }
    };

    // ---- prologue: layer0 computes h0(0) from attn(0) only
    if (!lay1) {
        if (kh == 0) {
            do_partial<8,8>(G, attnH, attnL, attnH, attnL);
            pubA(1);
        } else {
            do_partial<0,0>(G, attnH, attnL, attnH, attnL);   // zeros
            finishB(h0h, h0l, 1);
        }
    }
    hybrid_bar(flags, epoch, 1);

    // ---- pipelined: layer1(t) || layer0(t+1), t = 0..254
    for (int t = 0; t <= SEQT - 2; ++t) {
        if (lay1) {
            const int p = t & 1, q = p ^ 1;
            if (kh == 0) {
                do_partial<16,16>(G, h0h + (size_t)p*BH, h0l + (size_t)p*BH,
                                     h0h + (size_t)p*BH, h0l + (size_t)p*BH);
                pubA(t + 2);
            } else {
                if (t == 0)
                    do_partial<0,0>(G, h1h, h1l, h1h, h1l);   // h1(-1)=0
                else
                    do_partial<16,16>(G, h1h + (size_t)q*BH, h1l + (size_t)q*BH,
                                         h1h + (size_t)q*BH, h1l + (size_t)q*BH);
                finishB(h1h + (size_t)p*BH, h1l + (size_t)p*BH, t + 2);
            }
        } else {
            if (kh == 0) {
                if (t <= SEQT - 3) {
                    const int tt = t + 1, p = t & 1;
                    do_partial<8,12>(G, attnH + (size_t)tt*65536,
                                        attnL + (size_t)tt*65536,
                                        h0h + (size_t)p*BH, h0l + (size_t)p*BH);
                    pubA(t + 2);
                }
                if (t >= 1) {
                    const int q = (t - 1) & 1;
                    proj(h1h + (size_t)q*BH, h1l + (size_t)q*BH, t - 1);
                }
            } else {
                if (t <= SEQT - 3) {
                    const int tt = t + 1, p = t & 1, d = tt & 1;
                    // K-half 1 = h0 cols 128..511 -> source offset 16 chunks
                    do_partial<0,12>(G, h0h, h0l,
                                        h0h + (size_t)p*BH + 32768,
                                        h0l + (size_t)p*BH + 32768);
                    finishB(h0h + (size_t)d*BH, h0l + (size_t)d*BH, t + 2);
                }
            }
        }
        hybrid_bar(flags, epoch, t + 2);
    }

    // ---- tail: project h1(254) (parity 0)
    if (!lay1 && kh == 0) proj(h1h, h1l, TOUT - 1);
}

// ---------------------------------------------------------------------------
extern "C" void kernel_launch(void* const* d_in, const int* in_sizes, int n_in,
                              void* d_out, int out_size, void* d_ws, size_t ws_size,
                              hipStream_t stream)
{
    (void)in_sizes; (void)n_in; (void)out_size; (void)ws_size;
    const float* x     = (const float*)d_in[0];
    const float* wq    = (const float*)d_in[1];
    const float* wk    = (const float*)d_in[2];
    const float* wv    = (const float*)d_in[3];
    const float* w_fc  = (const float*)d_in[4];
    const float* b_fc  = (const float*)d_in[5];
    const float* w_hid = (const float*)d_in[6];
    const float* b_hid = (const float*)d_in[7];
    const float* w_ih  = (const float*)d_in[8];
    const float* w_hh  = (const float*)d_in[9];
    const float* b_ih  = (const float*)d_in[10];
    const float* b_hh  = (const float*)d_in[11];
    const float* w_out = (const float*)d_in[12];
    const float* b_out = (const float*)d_in[13];

    float* ws = (float*)d_ws;
    size_t off = 0;
    u16* attnH = (u16*)(ws + off); off += (size_t)SEQT*BATCH*FEATD/2;
    u16* attnL = (u16*)(ws + off); off += (size_t)SEQT*BATCH*FEATD/2;
    float* Wc  = ws + off; off += (size_t)HID*FEATD;
    float* bc  = ws + off; off += HID;
    float* Wx0 = ws + off; off += (size_t)GATES*FEATD;
    float* bx0 = ws + off; off += GATES;
    u16* h0h = (u16*)(ws + off); off += BH;    // 2 parity slabs (BH halves each)
    u16* h0l = (u16*)(ws + off); off += BH;
    u16* h1h = (u16*)(ws + off); off += BH;
    u16* h1l = (u16*)(ws + off); off += BH;
    int* flags    = (int*)(ws + off); off += 512;
    int* epoch    = (int*)(ws + off); off += 64;
    int* pairflag = (int*)(ws + off); off += 256;
    float* Pbuf   = ws + off; off += (size_t)256 * 4096;   // 4 MB partials

    hipMemsetAsync(flags, 0, (512 + 64 + 256)*sizeof(int), stream);

    k_attn  <<<dim3(BATCH*NHEADS), dim3(256), 0, stream>>>(x, wq, wk, wv, attnH, attnL);
    k_wcomb <<<dim3(64),           dim3(256), 0, stream>>>(w_fc, b_fc, w_hid, b_hid, Wc, bc);
    k_wx0   <<<dim3(256),          dim3(256), 0, stream>>>(w_ih, Wc, bc, b_ih, b_hh, Wx0, bx0);

    const int shmem = 32768 + 256*17*4;   // weights (32KB) + Cb (17.4KB) = 50176 B
    (void)hipFuncSetAttribute(reinterpret_cast<const void*>(k_lstm),
                              hipFuncAttributeMaxDynamicSharedMemorySize, shmem);
    k_lstm <<<dim3(NBLK), dim3(THR), (size_t)shmem, stream>>>(
        attnH, attnL, Wx0, bx0, h0h, h0l, h1h, h1l,
        w_ih, w_hh, b_ih, b_hh, w_out, b_out, (float*)d_out,
        flags, epoch, pairflag, Pbuf);
}

// Round 12
// 10104.064 us; speedup vs baseline: 1.8611x; 1.8611x over previous
//
#include <hip/hip_runtime.h>
#include <math.h>

// Problem constants
#define BATCH  256
#define SEQT   256
#define FEATD  256
#define NHEADS 8
#define HD     32
#define HID    512
#define GATES  2048
#define BH     (BATCH*HID)       // halves per h plane parity slab
#define TOUT   (SEQT-1)
#define NBLK   256
#define THR    1024
#define DEPTH  10                // prefetch depth (slices); 20 uint4 buffers

typedef __attribute__((ext_vector_type(8))) short short8;
typedef __attribute__((ext_vector_type(4))) float f32x4;
typedef unsigned short u16;

union U8 { uint4 u4; short8 s8; };

__device__ __forceinline__ float sigm(float x)     { return 1.f / (1.f + __expf(-x)); }
__device__ __forceinline__ float tanhfast(float x) { return 1.f - 2.f / (1.f + __expf(2.f * x)); }

__device__ __forceinline__ u16 bf16rn(float f) {
    union { float f; unsigned u; } v; v.f = f;
    unsigned r = v.u + 0x7fffu + ((v.u >> 16) & 1u);
    return (u16)(r >> 16);
}
__device__ __forceinline__ float bf2f(u16 h) {
    union { float f; unsigned u; } v; v.u = ((unsigned)h) << 16; return v.f;
}

// ---------------------------------------------------------------------------
// Fused per-(n,h) attention (verified rounds 2-10). Output T-major CB8:
// attn[t][cb8=f/8][n][8] split bf16 hi/lo planes (65536 halves per t-slice).
// ---------------------------------------------------------------------------
__global__ __launch_bounds__(256) void k_attn(
    const float* __restrict__ x,  const float* __restrict__ wq,
    const float* __restrict__ wk, const float* __restrict__ wv,
    u16* __restrict__ attnH, u16* __restrict__ attnL)
{
    __shared__ float Ks[128][40];
    __shared__ float Vs[128][40];

    const int nb  = blockIdx.x;
    const int n   = nb >> 3, h = nb & 7;
    const int tid = threadIdx.x;
    const float* xbase = x + ((size_t)n * SEQT) * FEATD + h * HD;

    float qv[HD];
    {
        float xr[HD];
        const float4* xp = (const float4*)(xbase + (size_t)tid * FEATD);
        #pragma unroll
        for (int q4 = 0; q4 < 8; ++q4) {
            float4 v = xp[q4];
            xr[q4*4+0] = v.x; xr[q4*4+1] = v.y; xr[q4*4+2] = v.z; xr[q4*4+3] = v.w;
        }
        #pragma unroll
        for (int d = 0; d < HD; ++d) {
            float s = 0.f;
            #pragma unroll
            for (int e = 0; e < HD; ++e) s += xr[e] * wq[d*HD + e];
            qv[d] = s * 0.0625f;
        }
    }

    float o[HD];
    #pragma unroll
    for (int d = 0; d < HD; ++d) o[d] = 0.f;
    float m = -1e30f, ssum = 0.f;

    for (int tile = 0; tile < 2; ++tile) {
        const int j0 = tile * 128;
        __syncthreads();
        {
            const int r = tid & 127;
            const float* W = (tid < 128) ? wk : wv;
            float xt[HD];
            const float4* xp = (const float4*)(xbase + (size_t)(j0 + r) * FEATD);
            #pragma unroll
            for (int q4 = 0; q4 < 8; ++q4) {
                float4 v = xp[q4];
                xt[q4*4+0] = v.x; xt[q4*4+1] = v.y; xt[q4*4+2] = v.z; xt[q4*4+3] = v.w;
            }
            float outr[HD];
            #pragma unroll
            for (int d = 0; d < HD; ++d) {
                float s = 0.f;
                #pragma unroll
                for (int e = 0; e < HD; ++e) s += xt[e] * W[d*HD + e];
                outr[d] = s;
            }
            float (*dst)[40] = (tid < 128) ? Ks : Vs;
            #pragma unroll
            for (int d = 0; d < HD; ++d) dst[r][d] = outr[d];
        }
        __syncthreads();

        for (int j = 0; j < 128; ++j) {
            float e = 0.f;
            #pragma unroll
            for (int dq = 0; dq < 8; ++dq) {
                float4 kq = *(const float4*)&Ks[j][dq*4];
                e += qv[dq*4+0]*kq.x + qv[dq*4+1]*kq.y
                   + qv[dq*4+2]*kq.z + qv[dq*4+3]*kq.w;
            }
            if (e > m) {
                float sc = __expf(m - e);
                ssum *= sc;
                #pragma unroll
                for (int d = 0; d < HD; ++d) o[d] *= sc;
                m = e;
            }
            float p = __expf(e - m);
            ssum += p;
            #pragma unroll
            for (int dq = 0; dq < 8; ++dq) {
                float4 vq = *(const float4*)&Vs[j][dq*4];
                o[dq*4+0] += p * vq.x; o[dq*4+1] += p * vq.y;
                o[dq*4+2] += p * vq.z; o[dq*4+3] += p * vq.w;
            }
        }
    }

    const float inv = 1.f / ssum;
    #pragma unroll
    for (int dq = 0; dq < 8; ++dq) {
        ushort4 vh, vl;
        float v0 = o[dq*4+0]*inv, v1 = o[dq*4+1]*inv,
              v2 = o[dq*4+2]*inv, v3 = o[dq*4+3]*inv;
        u16 a0 = bf16rn(v0); vh.x = a0; vl.x = bf16rn(v0 - bf2f(a0));
        u16 a1 = bf16rn(v1); vh.y = a1; vl.y = bf16rn(v1 - bf2f(a1));
        u16 a2 = bf16rn(v2); vh.z = a2; vl.z = bf16rn(v2 - bf2f(a2));
        u16 a3 = bf16rn(v3); vh.w = a3; vl.w = bf16rn(v3 - bf2f(a3));
        const size_t a = (size_t)tid*65536
                       + (size_t)(h*4 + (dq >> 1))*2048
                       + (size_t)n*8 + (dq & 1)*4;
        *(ushort4*)(attnH + a) = vh;
        *(ushort4*)(attnL + a) = vl;
    }
}

// ---------------------------------------------------------------------------
// Wc = w_hid @ w_fc [512,256]; bc = w_hid @ b_fc + b_hid.
// Tiled (verified R11): 8 rows/block, bit-identical summation order.
// ---------------------------------------------------------------------------
__global__ __launch_bounds__(256) void k_wcomb(
    const float* __restrict__ w_fc,  const float* __restrict__ b_fc,
    const float* __restrict__ w_hid, const float* __restrict__ b_hid,
    float* __restrict__ Wc, float* __restrict__ bc)
{
    __shared__ float wr[8][256];
    const int i0 = blockIdx.x * 8, tid = threadIdx.x;
    for (int e = tid; e < 8*256; e += 256)
        wr[e >> 8][e & 255] = w_hid[(size_t)(i0 + (e >> 8))*FEATD + (e & 255)];
    __syncthreads();
    const int j = tid;
    float acc[8] = {};
    for (int k = 0; k < FEATD; ++k) {
        const float wf = w_fc[(size_t)k*FEATD + j];
        #pragma unroll
        for (int i = 0; i < 8; ++i) acc[i] += wr[i][k] * wf;
    }
    #pragma unroll
    for (int i = 0; i < 8; ++i) Wc[(size_t)(i0 + i)*FEATD + j] = acc[i];
    if (tid < 8) {
        const int i = i0 + tid;
        float t = b_hid[i];
        for (int k = 0; k < FEATD; ++k) t += wr[tid][k] * b_fc[k];
        bc[i] = t;
    }
}

// ---------------------------------------------------------------------------
// Wx0 = W_ih[0] @ Wc [2048,256]; bx0 = W_ih[0] @ bc + b_ih[0] + b_hh[0].
// Tiled (verified R11): 8 rows/block, bit-identical summation order.
// ---------------------------------------------------------------------------
__global__ __launch_bounds__(256) void k_wx0(
    const float* __restrict__ w_ih, const float* __restrict__ Wc,
    const float* __restrict__ bc,   const float* __restrict__ b_ih,
    const float* __restrict__ b_hh,
    float* __restrict__ Wx0, float* __restrict__ bx0)
{
    __shared__ float wr[8][512];
    const int i0 = blockIdx.x * 8, tid = threadIdx.x;
    for (int e = tid; e < 8*512; e += 256)
        wr[e >> 9][e & 511] = w_ih[(size_t)(i0 + (e >> 9))*HID + (e & 511)];
    __syncthreads();
    const int j = tid;
    float acc[8] = {};
    for (int k = 0; k < HID; ++k) {
        const float wc = Wc[(size_t)k*FEATD + j];
        #pragma unroll
        for (int i = 0; i < 8; ++i) acc[i] += wr[i][k] * wc;
    }
    #pragma unroll
    for (int i = 0; i < 8; ++i) Wx0[(size_t)(i0 + i)*FEATD + j] = acc[i];
    if (tid < 8) {
        const int i = i0 + tid;
        float t = b_ih[i] + b_hh[i];
        for (int k = 0; k < HID; ++k) t += wr[tid][k] * bc[k];
        bx0[i] = t;
    }
}

// ---------------------------------------------------------------------------
// Hybrid grid barrier (verified round 9): parallel flag arrive, block-0
// aggregator, single-word epoch poll. Fences as in rounds 3-10.
// ---------------------------------------------------------------------------
__device__ __forceinline__ void hybrid_bar(int* flags, int* epoch, int step)
{
    __syncthreads();
    if (threadIdx.x == 0) {
        __threadfence();   // release: h stores to coherence point first
        __hip_atomic_store(&flags[blockIdx.x], step,
                           __ATOMIC_RELEASE, __HIP_MEMORY_SCOPE_AGENT);
    }
    if (blockIdx.x == 0 && threadIdx.x < 64) {
        const int base = (int)threadIdx.x * 4;
        for (;;) {
            int a = __hip_atomic_load(&flags[base+0], __ATOMIC_RELAXED, __HIP_MEMORY_SCOPE_AGENT);
            int b = __hip_atomic_load(&flags[base+1], __ATOMIC_RELAXED, __HIP_MEMORY_SCOPE_AGENT);
            int c = __hip_atomic_load(&flags[base+2], __ATOMIC_RELAXED, __HIP_MEMORY_SCOPE_AGENT);
            int d = __hip_atomic_load(&flags[base+3], __ATOMIC_RELAXED, __HIP_MEMORY_SCOPE_AGENT);
            if (__all(a >= step && b >= step && c >= step && d >= step)) break;
            __builtin_amdgcn_s_sleep(2);
        }
        if (threadIdx.x == 0)
            __hip_atomic_store(epoch, step,
                               __ATOMIC_RELEASE, __HIP_MEMORY_SCOPE_AGENT);
    }
    if (threadIdx.x == 0) {
        while (__hip_atomic_load(epoch, __ATOMIC_RELAXED, __HIP_MEMORY_SCOPE_AGENT) < step)
            __builtin_amdgcn_s_sleep(2);
        __threadfence();   // acquire: invalidate stale cached h
    }
    __syncthreads();
}

// ---------------------------------------------------------------------------
struct Geo {
    const u16* wlh; const u16* wll;   // LDS weights, FRAGMENT-MAJOR layout
    float* Cb;                        // LDS gate bounce [128][33]
    int rowg;                         // global batch row of A fragment
    int aq;                           // k-quarter (lane>>4)
    int bbase;                        // B frag base: Ntile*NS*512 + lane*8
    int Mtile, col_local;             // C placement
    int erow, hcl;                    // epilogue row / h-col
    int cg, mg;                       // col-group, row-group
    const float* bsum;                // per-thread gate biases [4]
};

// One LSTM step. A = [s0 (NT0 slices) | s1], NT slices of K=32 total.
// CB8 source layout: elem (row,k) at (k>>3)*2048 + row*8 + (k&7).
// B from LDS fragment-major: lane l reads (bbase + s*512 + l*8) -> stride-1
// conflict-free ds_read_b128. Depth-DEPTH register prefetch.
// Bit-identical MFMA operand values to rounds 5-10.
template<int NT0, int NT>
__device__ __forceinline__ void do_step(
    const Geo& G,
    const u16* __restrict__ s0H, const u16* __restrict__ s0L,
    const u16* __restrict__ s1H, const u16* __restrict__ s1L,
    u16* __restrict__ dH, u16* __restrict__ dL, float& cr)
{
    uint4 pfH[DEPTH], pfL[DEPTH];

    auto ld = [&](int d, int s) {
        const u16* pH = (s < NT0) ? s0H : s1H;
        const u16* pL = (s < NT0) ? s0L : s1L;
        const int sl  = (s < NT0) ? s : s - NT0;
        const size_t a = ((size_t)(sl*4 + G.aq) << 11) + (size_t)G.rowg * 8;
        pfH[d] = *(const uint4*)(pH + a);
        pfL[d] = *(const uint4*)(pL + a);
    };

    constexpr int PRIME = (DEPTH < NT) ? DEPTH : NT;
    #pragma unroll
    for (int d = 0; d < PRIME; ++d) ld(d, d);

    f32x4 acc = {0.f, 0.f, 0.f, 0.f};
    #pragma unroll
    for (int s = 0; s < NT; ++s) {
        U8 ua, ul;
        ua.u4 = pfH[s % DEPTH];
        ul.u4 = pfL[s % DEPTH];
        if (s + DEPTH < NT) ld(s % DEPTH, s + DEPTH);
        const short8 bh = *(const short8*)(G.wlh + G.bbase + s*512);
        const short8 bl = *(const short8*)(G.wll + G.bbase + s*512);
        acc = __builtin_amdgcn_mfma_f32_16x16x32_bf16(ua.s8, bh, acc, 0,0,0);
        acc = __builtin_amdgcn_mfma_f32_16x16x32_bf16(ul.s8, bh, acc, 0,0,0);
        acc = __builtin_amdgcn_mfma_f32_16x16x32_bf16(ua.s8, bl, acc, 0,0,0);
    }

    // C fragments -> LDS bounce
    {
        const int crow = G.Mtile*16 + G.aq*4;
        #pragma unroll
        for (int r = 0; r < 4; ++r)
            G.Cb[(crow + r)*33 + G.col_local] = acc[r];
    }
    __syncthreads();

    // gates + cell update + split-bf16 h store (CB8 layout, block-private)
    {
        float g4[4];
        #pragma unroll
        for (int g = 0; g < 4; ++g) g4[g] = G.Cb[G.erow*33 + g*8 + G.hcl] + G.bsum[g];
        const float gi = sigm(g4[0]), gf = sigm(g4[1]);
        const float gg = tanhfast(g4[2]), go = sigm(g4[3]);
        cr = gf*cr + gi*gg;
        const float h = go * tanhfast(cr);
        const u16 hh = bf16rn(h);
        const u16 hl = bf16rn(h - bf2f(hh));
        const size_t a = ((size_t)G.cg << 11) + (size_t)(G.mg*128 + G.erow)*8 + G.hcl;
        dH[a] = hh; dL[a] = hl;
    }
}

// ---------------------------------------------------------------------------
// Persistent MFMA LSTM. 256 blocks x 1024 threads (16 waves, 4/SIMD —
// LDS-limited to 1 block/CU, so VGPR up to 128 is free; DEPTH=10 uses it).
// Layer 1: blocks 0..127; layer 0: blocks 128..255. Block = (cg 0..63, mg
// 0..1): 32 gate-cols (8 h-cols = one cb8) x 128 batch rows. Weights
// split-bf16 LDS-resident in FRAGMENT-MAJOR order (conflict-free B reads).
// A read direct global->regs, depth-10 pipeline. Hybrid barrier.
// ---------------------------------------------------------------------------
__global__ __launch_bounds__(THR, 1) void k_lstm(
    const u16* __restrict__ attnH, const u16* __restrict__ attnL,
    const float* __restrict__ Wx0, const float* __restrict__ bx0,
    u16* __restrict__ h0h, u16* __restrict__ h0l,
    u16* __restrict__ h1h, u16* __restrict__ h1l,
    const float* __restrict__ w_ih, const float* __restrict__ w_hh,
    const float* __restrict__ b_ih, const float* __restrict__ b_hh,
    const float* __restrict__ w_out, const float* __restrict__ b_out,
    float* __restrict__ out, int* __restrict__ flags, int* __restrict__ epoch)
{
    extern __shared__ char smem[];
    const int tid  = threadIdx.x;
    const int bx   = blockIdx.x;
    const bool lay1 = (bx < 128);
    const int idx  = lay1 ? bx : bx - 128;
    const int cg   = idx >> 1;
    const int mg   = idx & 1;
    const int KW   = lay1 ? 1024 : 768;
    const int NS   = KW >> 5;             // K-slices: 32 (L1) or 24 (L0)

    u16*   wlh = (u16*)smem;              // [2 ntile][NS][64 lane][8]
    u16*   wll = wlh + 2*NS*512;
    float* Cb  = (float*)(smem + 132096);

    const int wid = tid >> 6, l = tid & 63;
    const int Mtile = wid & 7, Ntile = wid >> 3;
    const int lr = l & 15, aq = l >> 4;

    Geo G;
    G.wlh = wlh; G.wll = wll; G.Cb = Cb;
    G.rowg = mg*128 + Mtile*16 + lr;
    G.aq = aq;
    G.Mtile = Mtile;
    G.col_local = Ntile*16 + lr;
    G.bbase = Ntile*NS*512 + l*8;
    G.erow = tid & 127; G.hcl = tid >> 7;
    G.cg = cg; G.mg = mg;

    // ---- stage weights once: split fp32 -> bf16 hi/lo, fragment-major.
    // Element (local col c, k) -> lane = ((k>>3)&3)*16 + (c&15),
    // idx = ((c>>4)*NS + (k>>5))*512 + lane*8 + (k&7).
    for (int c = 0; c < 32; ++c) {
        const int grow = (c >> 3)*HID + cg*8 + (c & 7);
        const float* src0; const float* src1; int klen0;
        if (lay1) {
            src0 = w_ih + (size_t)GATES*HID + (size_t)grow*HID; klen0 = 512;
            src1 = w_hh + (size_t)GATES*HID + (size_t)grow*HID;
        } else {
            src0 = Wx0 + (size_t)grow*FEATD;                    klen0 = 256;
            src1 = w_hh + (size_t)grow*HID;
        }
        const int fb = (c >> 4)*NS*512 + (c & 15)*8;
        for (int k = tid; k < KW; k += THR) {
            float f = (k < klen0) ? src0[k] : src1[k - klen0];
            u16 hi = bf16rn(f);
            const int fidx = fb + (k >> 5)*512 + (((k >> 3) & 3) << 7) + (k & 7);
            wlh[fidx] = hi;
            wll[fidx] = bf16rn(f - bf2f(hi));
        }
    }

    float bsum[4];
    #pragma unroll
    for (int g = 0; g < 4; ++g) {
        const int gidx = g*HID + cg*8 + G.hcl;
        bsum[g] = lay1 ? (b_ih[GATES + gidx] + b_hh[GATES + gidx]) : bx0[gidx];
    }
    G.bsum = bsum;
    float cr = 0.f;
    __syncthreads();

    // projection: rows 2*idx, 2*idx+1 (layer-0 blocks only)
    auto proj = [&](const u16* hH, const u16* hL, int tout) {
        if (tid < 256) {
            const int r = tid >> 7, j = (tid >> 4) & 7, ks = tid & 15;
            const int n = 2*idx + r;
            float s = 0.f;
            #pragma unroll
            for (int kk = 0; kk < 32; ++kk) {
                const int k = ks*32 + kk;
                const size_t a = (size_t)(k >> 3)*2048 + (size_t)n*8 + (k & 7);
                float hv = bf2f(hH[a]) + bf2f(hL[a]);
                hv = hv > 0.f ? hv : 0.f;
                s += hv * w_out[(size_t)j*HID + k];
            }
            s += __shfl_xor(s, 1); s += __shfl_xor(s, 2);
            s += __shfl_xor(s, 4); s += __shfl_xor(s, 8);
            if (ks == 0)
                out[(size_t)n*(TOUT*NHEADS) + (size_t)tout*NHEADS + j] = s + b_out[j];
        }
    };

    // ---- prologue: layer0 computes h0(0) from attn(0) only
    if (!lay1)
        do_step<8,8>(G, attnH, attnL, attnH, attnL, h0h, h0l, cr);
    hybrid_bar(flags, epoch, 1);

    // ---- pipelined: layer1(t) || layer0(t+1), t = 0..254
    for (int t = 0; t <= SEQT - 2; ++t) {
        if (lay1) {
            const int p = t & 1, q = p ^ 1;
            if (t == 0)
                do_step<16,16>(G, h0h + (size_t)p*BH, h0l + (size_t)p*BH,
                                  h1h + (size_t)q*BH, h1l + (size_t)q*BH,
                                  h1h + (size_t)p*BH, h1l + (size_t)p*BH, cr);
            else
                do_step<16,32>(G, h0h + (size_t)p*BH, h0l + (size_t)p*BH,
                                  h1h + (size_t)q*BH, h1l + (size_t)q*BH,
                                  h1h + (size_t)p*BH, h1l + (size_t)p*BH, cr);
        } else {
            if (t >= 1) {
                const int q = (t - 1) & 1;
                proj(h1h + (size_t)q*BH, h1l + (size_t)q*BH, t - 1);
            }
            if (t <= SEQT - 3) {
                const int tt = t + 1, p = t & 1, d = tt & 1;
                do_step<8,24>(G, attnH + (size_t)tt*65536, attnL + (size_t)tt*65536,
                                 h0h + (size_t)p*BH, h0l + (size_t)p*BH,
                                 h0h + (size_t)d*BH, h0l + (size_t)d*BH, cr);
            }
        }
        hybrid_bar(flags, epoch, t + 2);
    }

    // ---- tail: project h1(254) (parity 0)
    if (!lay1) proj(h1h, h1l, TOUT - 1);
}

// ---------------------------------------------------------------------------
extern "C" void kernel_launch(void* const* d_in, const int* in_sizes, int n_in,
                              void* d_out, int out_size, void* d_ws, size_t ws_size,
                              hipStream_t stream)
{
    (void)in_sizes; (void)n_in; (void)out_size; (void)ws_size;
    const float* x     = (const float*)d_in[0];
    const float* wq    = (const float*)d_in[1];
    const float* wk    = (const float*)d_in[2];
    const float* wv    = (const float*)d_in[3];
    const float* w_fc  = (const float*)d_in[4];
    const float* b_fc  = (const float*)d_in[5];
    const float* w_hid = (const float*)d_in[6];
    const float* b_hid = (const float*)d_in[7];
    const float* w_ih  = (const float*)d_in[8];
    const float* w_hh  = (const float*)d_in[9];
    const float* b_ih  = (const float*)d_in[10];
    const float* b_hh  = (const float*)d_in[11];
    const float* w_out = (const float*)d_in[12];
    const float* b_out = (const float*)d_in[13];

    float* ws = (float*)d_ws;
    size_t off = 0;
    u16* attnH = (u16*)(ws + off); off += (size_t)SEQT*BATCH*FEATD/2;
    u16* attnL = (u16*)(ws + off); off += (size_t)SEQT*BATCH*FEATD/2;
    float* Wc  = ws + off; off += (size_t)HID*FEATD;
    float* bc  = ws + off; off += HID;
    float* Wx0 = ws + off; off += (size_t)GATES*FEATD;
    float* bx0 = ws + off; off += GATES;
    u16* h0h = (u16*)(ws + off); off += BH;    // 2 parity slabs (BH halves each)
    u16* h0l = (u16*)(ws + off); off += BH;
    u16* h1h = (u16*)(ws + off); off += BH;
    u16* h1l = (u16*)(ws + off); off += BH;
    int* flags = (int*)(ws + off); off += 256;  // 256 flag slots
    int* epoch = (int*)(ws + off); off += 64;   // own cacheline

    hipMemsetAsync(flags, 0, (NBLK + 64)*sizeof(int), stream);

    k_attn  <<<dim3(BATCH*NHEADS), dim3(256), 0, stream>>>(x, wq, wk, wv, attnH, attnL);
    k_wcomb <<<dim3(64),           dim3(256), 0, stream>>>(w_fc, b_fc, w_hid, b_hid, Wc, bc);
    k_wx0   <<<dim3(256),          dim3(256), 0, stream>>>(w_ih, Wc, bc, b_ih, b_hh, Wx0, bx0);

    const int shmem = 132096 + 128*33*4;   // weights (L1 max: 128KB) + Cb
    (void)hipFuncSetAttribute(reinterpret_cast<const void*>(k_lstm),
                              hipFuncAttributeMaxDynamicSharedMemorySize, shmem);
    k_lstm <<<dim3(NBLK), dim3(THR), (size_t)shmem, stream>>>(
        attnH, attnL, Wx0, bx0, h0h, h0l, h1h, h1l,
        w_ih, w_hh, b_ih, b_hh, w_out, b_out, (float*)d_out, flags, epoch);
}

// Round 14
// 6919.168 us; speedup vs baseline: 2.7178x; 1.4603x over previous
//
#include <hip/hip_runtime.h>
#include <math.h>

// Problem constants
#define BATCH  256
#define SEQT   256
#define FEATD  256
#define NHEADS 8
#define HD     32
#define HID    512
#define GATES  2048
#define BH     (BATCH*HID)       // halves per h plane parity slab
#define TOUT   (SEQT-1)
#define NBLK   256
#define THR    1024
#define DEPTH  6                 // prefetch depth (slices)

typedef __attribute__((ext_vector_type(8))) short short8;
typedef __attribute__((ext_vector_type(4))) float f32x4;
typedef __attribute__((ext_vector_type(4))) unsigned int u32x4;
typedef unsigned short u16;

union U8 { uint4 u4; short8 s8; };

__device__ __forceinline__ float sigm(float x)     { return 1.f / (1.f + __expf(-x)); }
__device__ __forceinline__ float tanhfast(float x) { return 1.f - 2.f / (1.f + __expf(2.f * x)); }

__device__ __forceinline__ u16 bf16rn(float f) {
    union { float f; unsigned u; } v; v.f = f;
    unsigned r = v.u + 0x7fffu + ((v.u >> 16) & 1u);
    return (u16)(r >> 16);
}
__device__ __forceinline__ float bf2f(u16 h) {
    union { float f; unsigned u; } v; v.u = ((unsigned)h) << 16; return v.f;
}

// Device-scope (sc1) 16B store: writes through to the coherence point,
// bypassing the (non-cross-XCD-coherent) L2 -> no dirty h lines in L2,
// so no release writeback-walk is needed at the barrier.
// Address passed as 64-bit scalar (VGPR pair), payload as native ext-vector.
__device__ __forceinline__ void st16_dev(void* p, u32x4 v) {
    unsigned long long a = (unsigned long long)p;
    asm volatile("global_store_dwordx4 %0, %1, off sc1"
                 :: "v"(a), "v"(v) : "memory");
}

// ---------------------------------------------------------------------------
// Fused per-(n,h) attention (verified rounds 2-12). Output T-major CB8:
// attn[t][cb8=f/8][n][8] split bf16 hi/lo planes (65536 halves per t-slice).
// ---------------------------------------------------------------------------
__global__ __launch_bounds__(256) void k_attn(
    const float* __restrict__ x,  const float* __restrict__ wq,
    const float* __restrict__ wk, const float* __restrict__ wv,
    u16* __restrict__ attnH, u16* __restrict__ attnL)
{
    __shared__ float Ks[128][40];
    __shared__ float Vs[128][40];

    const int nb  = blockIdx.x;
    const int n   = nb >> 3, h = nb & 7;
    const int tid = threadIdx.x;
    const float* xbase = x + ((size_t)n * SEQT) * FEATD + h * HD;

    float qv[HD];
    {
        float xr[HD];
        const float4* xp = (const float4*)(xbase + (size_t)tid * FEATD);
        #pragma unroll
        for (int q4 = 0; q4 < 8; ++q4) {
            float4 v = xp[q4];
            xr[q4*4+0] = v.x; xr[q4*4+1] = v.y; xr[q4*4+2] = v.z; xr[q4*4+3] = v.w;
        }
        #pragma unroll
        for (int d = 0; d < HD; ++d) {
            float s = 0.f;
            #pragma unroll
            for (int e = 0; e < HD; ++e) s += xr[e] * wq[d*HD + e];
            qv[d] = s * 0.0625f;
        }
    }

    float o[HD];
    #pragma unroll
    for (int d = 0; d < HD; ++d) o[d] = 0.f;
    float m = -1e30f, ssum = 0.f;

    for (int tile = 0; tile < 2; ++tile) {
        const int j0 = tile * 128;
        __syncthreads();
        {
            const int r = tid & 127;
            const float* W = (tid < 128) ? wk : wv;
            float xt[HD];
            const float4* xp = (const float4*)(xbase + (size_t)(j0 + r) * FEATD);
            #pragma unroll
            for (int q4 = 0; q4 < 8; ++q4) {
                float4 v = xp[q4];
                xt[q4*4+0] = v.x; xt[q4*4+1] = v.y; xt[q4*4+2] = v.z; xt[q4*4+3] = v.w;
            }
            float outr[HD];
            #pragma unroll
            for (int d = 0; d < HD; ++d) {
                float s = 0.f;
                #pragma unroll
                for (int e = 0; e < HD; ++e) s += xt[e] * W[d*HD + e];
                outr[d] = s;
            }
            float (*dst)[40] = (tid < 128) ? Ks : Vs;
            #pragma unroll
            for (int d = 0; d < HD; ++d) dst[r][d] = outr[d];
        }
        __syncthreads();

        for (int j = 0; j < 128; ++j) {
            float e = 0.f;
            #pragma unroll
            for (int dq = 0; dq < 8; ++dq) {
                float4 kq = *(const float4*)&Ks[j][dq*4];
                e += qv[dq*4+0]*kq.x + qv[dq*4+1]*kq.y
                   + qv[dq*4+2]*kq.z + qv[dq*4+3]*kq.w;
            }
            if (e > m) {
                float sc = __expf(m - e);
                ssum *= sc;
                #pragma unroll
                for (int d = 0; d < HD; ++d) o[d] *= sc;
                m = e;
            }
            float p = __expf(e - m);
            ssum += p;
            #pragma unroll
            for (int dq = 0; dq < 8; ++dq) {
                float4 vq = *(const float4*)&Vs[j][dq*4];
                o[dq*4+0] += p * vq.x; o[dq*4+1] += p * vq.y;
                o[dq*4+2] += p * vq.z; o[dq*4+3] += p * vq.w;
            }
        }
    }

    const float inv = 1.f / ssum;
    #pragma unroll
    for (int dq = 0; dq < 8; ++dq) {
        ushort4 vh, vl;
        float v0 = o[dq*4+0]*inv, v1 = o[dq*4+1]*inv,
              v2 = o[dq*4+2]*inv, v3 = o[dq*4+3]*inv;
        u16 a0 = bf16rn(v0); vh.x = a0; vl.x = bf16rn(v0 - bf2f(a0));
        u16 a1 = bf16rn(v1); vh.y = a1; vl.y = bf16rn(v1 - bf2f(a1));
        u16 a2 = bf16rn(v2); vh.z = a2; vl.z = bf16rn(v2 - bf2f(a2));
        u16 a3 = bf16rn(v3); vh.w = a3; vl.w = bf16rn(v3 - bf2f(a3));
        const size_t a = (size_t)tid*65536
                       + (size_t)(h*4 + (dq >> 1))*2048
                       + (size_t)n*8 + (dq & 1)*4;
        *(ushort4*)(attnH + a) = vh;
        *(ushort4*)(attnL + a) = vl;
    }
}

// ---------------------------------------------------------------------------
// Wc = w_hid @ w_fc [512,256]; bc = w_hid @ b_fc + b_hid.
// Tiled (verified R11/R12): 8 rows/block, bit-identical summation order.
// ---------------------------------------------------------------------------
__global__ __launch_bounds__(256) void k_wcomb(
    const float* __restrict__ w_fc,  const float* __restrict__ b_fc,
    const float* __restrict__ w_hid, const float* __restrict__ b_hid,
    float* __restrict__ Wc, float* __restrict__ bc)
{
    __shared__ float wr[8][256];
    const int i0 = blockIdx.x * 8, tid = threadIdx.x;
    for (int e = tid; e < 8*256; e += 256)
        wr[e >> 8][e & 255] = w_hid[(size_t)(i0 + (e >> 8))*FEATD + (e & 255)];
    __syncthreads();
    const int j = tid;
    float acc[8] = {};
    for (int k = 0; k < FEATD; ++k) {
        const float wf = w_fc[(size_t)k*FEATD + j];
        #pragma unroll
        for (int i = 0; i < 8; ++i) acc[i] += wr[i][k] * wf;
    }
    #pragma unroll
    for (int i = 0; i < 8; ++i) Wc[(size_t)(i0 + i)*FEATD + j] = acc[i];
    if (tid < 8) {
        const int i = i0 + tid;
        float t = b_hid[i];
        for (int k = 0; k < FEATD; ++k) t += wr[tid][k] * b_fc[k];
        bc[i] = t;
    }
}

// ---------------------------------------------------------------------------
// Wx0 = W_ih[0] @ Wc [2048,256]; bx0 = W_ih[0] @ bc + b_ih[0] + b_hh[0].
// Tiled (verified R11/R12): 8 rows/block, bit-identical summation order.
// ---------------------------------------------------------------------------
__global__ __launch_bounds__(256) void k_wx0(
    const float* __restrict__ w_ih, const float* __restrict__ Wc,
    const float* __restrict__ bc,   const float* __restrict__ b_ih,
    const float* __restrict__ b_hh,
    float* __restrict__ Wx0, float* __restrict__ bx0)
{
    __shared__ float wr[8][512];
    const int i0 = blockIdx.x * 8, tid = threadIdx.x;
    for (int e = tid; e < 8*512; e += 256)
        wr[e >> 9][e & 511] = w_ih[(size_t)(i0 + (e >> 9))*HID + (e & 511)];
    __syncthreads();
    const int j = tid;
    float acc[8] = {};
    for (int k = 0; k < HID; ++k) {
        const float wc = Wc[(size_t)k*FEATD + j];
        #pragma unroll
        for (int i = 0; i < 8; ++i) acc[i] += wr[i][k] * wc;
    }
    #pragma unroll
    for (int i = 0; i < 8; ++i) Wx0[(size_t)(i0 + i)*FEATD + j] = acc[i];
    if (tid < 8) {
        const int i = i0 + tid;
        float t = b_ih[i] + b_hh[i];
        for (int k = 0; k < HID; ++k) t += wr[tid][k] * bc[k];
        bx0[i] = t;
    }
}

// ---------------------------------------------------------------------------
// Hybrid grid barrier v2 (arrive/aggregate/poll structure verified R9-R12).
// Release side: h-data was stored with sc1 (already at coherence point), so
// release = per-thread vmcnt(0) drain + relaxed flag store. No L2 writeback.
// Acquire side: one agent-scope acquire fence (L1+L2 invalidate) per block,
// so subsequent cached A-loads refetch fresh lines; same-XCD blocks then
// share them in L2.
// ---------------------------------------------------------------------------
__device__ __forceinline__ void hybrid_bar(int* flags, int* epoch, int step)
{
    asm volatile("s_waitcnt vmcnt(0)" ::: "memory");   // drain own sc1 stores
    __syncthreads();                                    // all threads drained
    if (threadIdx.x == 0)
        __hip_atomic_store(&flags[blockIdx.x], step,
                           __ATOMIC_RELAXED, __HIP_MEMORY_SCOPE_AGENT);
    if (blockIdx.x == 0 && threadIdx.x < 64) {
        const int base = (int)threadIdx.x * 4;
        for (;;) {
            int a = __hip_atomic_load(&flags[base+0], __ATOMIC_RELAXED, __HIP_MEMORY_SCOPE_AGENT);
            int b = __hip_atomic_load(&flags[base+1], __ATOMIC_RELAXED, __HIP_MEMORY_SCOPE_AGENT);
            int c = __hip_atomic_load(&flags[base+2], __ATOMIC_RELAXED, __HIP_MEMORY_SCOPE_AGENT);
            int d = __hip_atomic_load(&flags[base+3], __ATOMIC_RELAXED, __HIP_MEMORY_SCOPE_AGENT);
            if (__all(a >= step && b >= step && c >= step && d >= step)) break;
            __builtin_amdgcn_s_sleep(2);
        }
        if (threadIdx.x == 0)
            __hip_atomic_store(epoch, step,
                               __ATOMIC_RELAXED, __HIP_MEMORY_SCOPE_AGENT);
    }
    if (threadIdx.x == 0) {
        while (__hip_atomic_load(epoch, __ATOMIC_RELAXED, __HIP_MEMORY_SCOPE_AGENT) < step)
            __builtin_amdgcn_s_sleep(2);
        __builtin_amdgcn_fence(__ATOMIC_ACQUIRE, "agent");  // inv L1+L2 (no wb)
    }
    __syncthreads();
}

// ---------------------------------------------------------------------------
struct Geo {
    const u16* wlh; const u16* wll;   // LDS weights, FRAGMENT-MAJOR layout
    float* Cb;                        // LDS gate bounce [128][33]
    u16* hb;                          // LDS h-store bounce [2][128][8]
    int tid;
    int rowg;                         // global batch row of A fragment
    int aq;                           // k-quarter (lane>>4)
    int bbase;                        // B frag base: Ntile*NS*512 + lane*8
    int Mtile, col_local;             // C placement
    int erow, hcl;                    // epilogue row / h-col
    int cg, mg;                       // col-group, row-group
    const float* bsum;                // per-thread gate biases [4]
};

// One LSTM step. A = [s0 (NT0 slices) | s1], NT slices of K=32 total.
// CB8 source layout: elem (row,k) at (k>>3)*2048 + row*8 + (k&7).
// B from LDS fragment-major (conflict-free). A-loads NORMAL (L2-cached;
// freshness via per-step acquire inv). h stored via LDS write-combine ->
// 256 x 16B sc1 device-scope stores (L2 never dirty).
// Bit-identical MFMA operand values to rounds 5-12.
template<int NT0, int NT>
__device__ __forceinline__ void do_step(
    const Geo& G,
    const u16* __restrict__ s0H, const u16* __restrict__ s0L,
    const u16* __restrict__ s1H, const u16* __restrict__ s1L,
    u16* __restrict__ dH, u16* __restrict__ dL, float& cr)
{
    uint4 pfH[DEPTH], pfL[DEPTH];

    auto ld = [&](int d, int s) {
        const u16* pH = (s < NT0) ? s0H : s1H;
        const u16* pL = (s < NT0) ? s0L : s1L;
        const int sl  = (s < NT0) ? s : s - NT0;
        const size_t a = ((size_t)(sl*4 + G.aq) << 11) + (size_t)G.rowg * 8;
        pfH[d] = *(const uint4*)(pH + a);
        pfL[d] = *(const uint4*)(pL + a);
    };

    constexpr int PRIME = (DEPTH < NT) ? DEPTH : NT;
    #pragma unroll
    for (int d = 0; d < PRIME; ++d) ld(d, d);

    f32x4 acc = {0.f, 0.f, 0.f, 0.f};
    #pragma unroll
    for (int s = 0; s < NT; ++s) {
        U8 ua, ul;
        ua.u4 = pfH[s % DEPTH];
        ul.u4 = pfL[s % DEPTH];
        if (s + DEPTH < NT) ld(s % DEPTH, s + DEPTH);
        const short8 bh = *(const short8*)(G.wlh + G.bbase + s*512);
        const short8 bl = *(const short8*)(G.wll + G.bbase + s*512);
        acc = __builtin_amdgcn_mfma_f32_16x16x32_bf16(ua.s8, bh, acc, 0,0,0);
        acc = __builtin_amdgcn_mfma_f32_16x16x32_bf16(ul.s8, bh, acc, 0,0,0);
        acc = __builtin_amdgcn_mfma_f32_16x16x32_bf16(ua.s8, bl, acc, 0,0,0);
    }

    // C fragments -> LDS bounce
    {
        const int crow = G.Mtile*16 + G.aq*4;
        #pragma unroll
        for (int r = 0; r < 4; ++r)
            G.Cb[(crow + r)*33 + G.col_local] = acc[r];
    }
    __syncthreads();

    // gates + cell update; h halves staged in LDS for coalesced dev-stores
    {
        float g4[4];
        #pragma unroll
        for (int g = 0; g < 4; ++g) g4[g] = G.Cb[G.erow*33 + g*8 + G.hcl] + G.bsum[g];
        const float gi = sigm(g4[0]), gf = sigm(g4[1]);
        const float gg = tanhfast(g4[2]), go = sigm(g4[3]);
        cr = gf*cr + gi*gg;
        const float h = go * tanhfast(cr);
        const u16 hh = bf16rn(h);
        const u16 hl = bf16rn(h - bf2f(hh));
        G.hb[G.erow*8 + G.hcl]        = hh;
        G.hb[1024 + G.erow*8 + G.hcl] = hl;
    }
    __syncthreads();

    // 256 coalesced 16B device-scope stores (write-through, L2 stays clean)
    if (G.tid < 256) {
        const int row = G.tid & 127, pl = G.tid >> 7;
        const u32x4 v = *(const u32x4*)&G.hb[pl*1024 + row*8];
        u16* dst = pl ? dL : dH;
        st16_dev(dst + ((size_t)G.cg << 11) + (size_t)(G.mg*128 + row)*8, v);
    }
}

// ---------------------------------------------------------------------------
// Persistent MFMA LSTM. 256 blocks x 1024 threads (16 waves, 4/SIMD).
// Layer 1: blocks 0..127; layer 0: blocks 128..255. Block = (cg 0..63, mg
// 0..1): 32 gate-cols (8 h-cols = one cb8) x 128 batch rows. Weights
// split-bf16 LDS-resident fragment-major. A read direct global->regs,
// L2-cached (same-XCD blocks share the A panel in L2 after one acquire inv
// per step). h write-through sc1. Hybrid barrier v2 (no L2 writeback walks).
// ---------------------------------------------------------------------------
__global__ __launch_bounds__(THR, 1) void k_lstm(
    const u16* __restrict__ attnH, const u16* __restrict__ attnL,
    const float* __restrict__ Wx0, const float* __restrict__ bx0,
    u16* __restrict__ h0h, u16* __restrict__ h0l,
    u16* __restrict__ h1h, u16* __restrict__ h1l,
    const float* __restrict__ w_ih, const float* __restrict__ w_hh,
    const float* __restrict__ b_ih, const float* __restrict__ b_hh,
    const float* __restrict__ w_out, const float* __restrict__ b_out,
    float* __restrict__ out, int* __restrict__ flags, int* __restrict__ epoch)
{
    extern __shared__ char smem[];
    const int tid  = threadIdx.x;
    const int bx   = blockIdx.x;
    const bool lay1 = (bx < 128);
    const int idx  = lay1 ? bx : bx - 128;
    const int cg   = idx >> 1;
    const int mg   = idx & 1;
    const int KW   = lay1 ? 1024 : 768;
    const int NS   = KW >> 5;             // K-slices: 32 (L1) or 24 (L0)

    u16*   wlh = (u16*)smem;              // [2 ntile][NS][64 lane][8]
    u16*   wll = wlh + 2*NS*512;
    float* Cb  = (float*)(smem + 132096);
    u16*   hb  = (u16*)(smem + 148992);   // [2][128][8] halves (4KB)

    const int wid = tid >> 6, l = tid & 63;
    const int Mtile = wid & 7, Ntile = wid >> 3;
    const int lr = l & 15, aq = l >> 4;

    Geo G;
    G.wlh = wlh; G.wll = wll; G.Cb = Cb; G.hb = hb; G.tid = tid;
    G.rowg = mg*128 + Mtile*16 + lr;
    G.aq = aq;
    G.Mtile = Mtile;
    G.col_local = Ntile*16 + lr;
    G.bbase = Ntile*NS*512 + l*8;
    G.erow = tid & 127; G.hcl = tid >> 7;
    G.cg = cg; G.mg = mg;

    // ---- stage weights once: split fp32 -> bf16 hi/lo, fragment-major.
    for (int c = 0; c < 32; ++c) {
        const int grow = (c >> 3)*HID + cg*8 + (c & 7);
        const float* src0; const float* src1; int klen0;
        if (lay1) {
            src0 = w_ih + (size_t)GATES*HID + (size_t)grow*HID; klen0 = 512;
            src1 = w_hh + (size_t)GATES*HID + (size_t)grow*HID;
        } else {
            src0 = Wx0 + (size_t)grow*FEATD;                    klen0 = 256;
            src1 = w_hh + (size_t)grow*HID;
        }
        const int fb = (c >> 4)*NS*512 + (c & 15)*8;
        for (int k = tid; k < KW; k += THR) {
            float f = (k < klen0) ? src0[k] : src1[k - klen0];
            u16 hi = bf16rn(f);
            const int fidx = fb + (k >> 5)*512 + (((k >> 3) & 3) << 7) + (k & 7);
            wlh[fidx] = hi;
            wll[fidx] = bf16rn(f - bf2f(hi));
        }
    }

    float bsum[4];
    #pragma unroll
    for (int g = 0; g < 4; ++g) {
        const int gidx = g*HID + cg*8 + G.hcl;
        bsum[g] = lay1 ? (b_ih[GATES + gidx] + b_hh[GATES + gidx]) : bx0[gidx];
    }
    G.bsum = bsum;
    float cr = 0.f;
    __syncthreads();

    // projection: rows 2*idx, 2*idx+1 (layer-0 blocks only)
    auto proj = [&](const u16* hH, const u16* hL, int tout) {
        if (tid < 256) {
            const int r = tid >> 7, j = (tid >> 4) & 7, ks = tid & 15;
            const int n = 2*idx + r;
            float s = 0.f;
            #pragma unroll
            for (int kk = 0; kk < 32; ++kk) {
                const int k = ks*32 + kk;
                const size_t a = (size_t)(k >> 3)*2048 + (size_t)n*8 + (k & 7);
                float hv = bf2f(hH[a]) + bf2f(hL[a]);
                hv = hv > 0.f ? hv : 0.f;
                s += hv * w_out[(size_t)j*HID + k];
            }
            s += __shfl_xor(s, 1); s += __shfl_xor(s, 2);
            s += __shfl_xor(s, 4); s += __shfl_xor(s, 8);
            if (ks == 0)
                out[(size_t)n*(TOUT*NHEADS) + (size_t)tout*NHEADS + j] = s + b_out[j];
        }
    };

    // ---- prologue: layer0 computes h0(0) from attn(0) only
    if (!lay1)
        do_step<8,8>(G, attnH, attnL, attnH, attnL, h0h, h0l, cr);
    hybrid_bar(flags, epoch, 1);

    // ---- pipelined: layer1(t) || layer0(t+1), t = 0..254
    for (int t = 0; t <= SEQT - 2; ++t) {
        if (lay1) {
            const int p = t & 1, q = p ^ 1;
            if (t == 0)
                do_step<16,16>(G, h0h + (size_t)p*BH, h0l + (size_t)p*BH,
                                  h1h + (size_t)q*BH, h1l + (size_t)q*BH,
                                  h1h + (size_t)p*BH, h1l + (size_t)p*BH, cr);
            else
                do_step<16,32>(G, h0h + (size_t)p*BH, h0l + (size_t)p*BH,
                                  h1h + (size_t)q*BH, h1l + (size_t)q*BH,
                                  h1h + (size_t)p*BH, h1l + (size_t)p*BH, cr);
        } else {
            if (t >= 1) {
                const int q = (t - 1) & 1;
                proj(h1h + (size_t)q*BH, h1l + (size_t)q*BH, t - 1);
            }
            if (t <= SEQT - 3) {
                const int tt = t + 1, p = t & 1, d = tt & 1;
                do_step<8,24>(G, attnH + (size_t)tt*65536, attnL + (size_t)tt*65536,
                                 h0h + (size_t)p*BH, h0l + (size_t)p*BH,
                                 h0h + (size_t)d*BH, h0l + (size_t)d*BH, cr);
            }
        }
        hybrid_bar(flags, epoch, t + 2);
    }

    // ---- tail: project h1(254) (parity 0)
    if (!lay1) proj(h1h, h1l, TOUT - 1);
}

// ---------------------------------------------------------------------------
extern "C" void kernel_launch(void* const* d_in, const int* in_sizes, int n_in,
                              void* d_out, int out_size, void* d_ws, size_t ws_size,
                              hipStream_t stream)
{
    (void)in_sizes; (void)n_in; (void)out_size; (void)ws_size;
    const float* x     = (const float*)d_in[0];
    const float* wq    = (const float*)d_in[1];
    const float* wk    = (const float*)d_in[2];
    const float* wv    = (const float*)d_in[3];
    const float* w_fc  = (const float*)d_in[4];
    const float* b_fc  = (const float*)d_in[5];
    const float* w_hid = (const float*)d_in[6];
    const float* b_hid = (const float*)d_in[7];
    const float* w_ih  = (const float*)d_in[8];
    const float* w_hh  = (const float*)d_in[9];
    const float* b_ih  = (const float*)d_in[10];
    const float* b_hh  = (const float*)d_in[11];
    const float* w_out = (const float*)d_in[12];
    const float* b_out = (const float*)d_in[13];

    float* ws = (float*)d_ws;
    size_t off = 0;
    u16* attnH = (u16*)(ws + off); off += (size_t)SEQT*BATCH*FEATD/2;
    u16* attnL = (u16*)(ws + off); off += (size_t)SEQT*BATCH*FEATD/2;
    float* Wc  = ws + off; off += (size_t)HID*FEATD;
    float* bc  = ws + off; off += HID;
    float* Wx0 = ws + off; off += (size_t)GATES*FEATD;
    float* bx0 = ws + off; off += GATES;
    u16* h0h = (u16*)(ws + off); off += BH;    // 2 parity slabs (BH halves each)
    u16* h0l = (u16*)(ws + off); off += BH;
    u16* h1h = (u16*)(ws + off); off += BH;
    u16* h1l = (u16*)(ws + off); off += BH;
    int* flags = (int*)(ws + off); off += 256;  // 256 flag slots
    int* epoch = (int*)(ws + off); off += 64;   // own cacheline

    (void)hipMemsetAsync(flags, 0, (NBLK + 64)*sizeof(int), stream);

    k_attn  <<<dim3(BATCH*NHEADS), dim3(256), 0, stream>>>(x, wq, wk, wv, attnH, attnL);
    k_wcomb <<<dim3(64),           dim3(256), 0, stream>>>(w_fc, b_fc, w_hid, b_hid, Wc, bc);
    k_wx0   <<<dim3(256),          dim3(256), 0, stream>>>(w_ih, Wc, bc, b_ih, b_hh, Wx0, bx0);

    const int shmem = 132096 + 128*33*4 + 4096;   // weights + Cb + h bounce
    (void)hipFuncSetAttribute(reinterpret_cast<const void*>(k_lstm),
                              hipFuncAttributeMaxDynamicSharedMemorySize, shmem);
    k_lstm <<<dim3(NBLK), dim3(THR), (size_t)shmem, stream>>>(
        attnH, attnL, Wx0, bx0, h0h, h0l, h1h, h1l,
        w_ih, w_hh, b_ih, b_hh, w_out, b_out, (float*)d_out, flags, epoch);
}

// Round 15
// 6456.104 us; speedup vs baseline: 2.9127x; 1.0717x over previous
//
#include <hip/hip_runtime.h>
#include <math.h>

// Problem constants
#define BATCH  256
#define SEQT   256
#define FEATD  256
#define NHEADS 8
#define HD     32
#define HID    512
#define GATES  2048
#define BH     (BATCH*HID)       // halves per h plane slab
#define TOUT   (SEQT-1)
#define NBLK   256
#define THR    1024
#define DEPTH  6                 // prefetch depth (slices)

typedef __attribute__((ext_vector_type(8))) short short8;
typedef __attribute__((ext_vector_type(4))) float f32x4;
typedef __attribute__((ext_vector_type(4))) unsigned int u32x4;
typedef unsigned short u16;

union U8 { uint4 u4; short8 s8; };

__device__ __forceinline__ float sigm(float x)     { return 1.f / (1.f + __expf(-x)); }
__device__ __forceinline__ float tanhfast(float x) { return 1.f - 2.f / (1.f + __expf(2.f * x)); }

__device__ __forceinline__ u16 bf16rn(float f) {
    union { float f; unsigned u; } v; v.f = f;
    unsigned r = v.u + 0x7fffu + ((v.u >> 16) & 1u);
    return (u16)(r >> 16);
}
__device__ __forceinline__ float bf2f(u16 h) {
    union { float f; unsigned u; } v; v.u = ((unsigned)h) << 16; return v.f;
}

// Device-scope (sc1) 16B store (verified R14): write-through to coherence
// point; L2 never holds dirty h lines -> no release writeback-walk needed.
__device__ __forceinline__ void st16_dev(void* p, u32x4 v) {
    unsigned long long a = (unsigned long long)p;
    asm volatile("global_store_dwordx4 %0, %1, off sc1"
                 :: "v"(a), "v"(v) : "memory");
}

// ---------------------------------------------------------------------------
// Fused per-(n,h) attention (verified rounds 2-14). Output T-major CB8:
// attn[t][cb8=f/8][n][8] split bf16 hi/lo planes (65536 halves per t-slice).
// ---------------------------------------------------------------------------
__global__ __launch_bounds__(256) void k_attn(
    const float* __restrict__ x,  const float* __restrict__ wq,
    const float* __restrict__ wk, const float* __restrict__ wv,
    u16* __restrict__ attnH, u16* __restrict__ attnL)
{
    __shared__ float Ks[128][40];
    __shared__ float Vs[128][40];

    const int nb  = blockIdx.x;
    const int n   = nb >> 3, h = nb & 7;
    const int tid = threadIdx.x;
    const float* xbase = x + ((size_t)n * SEQT) * FEATD + h * HD;

    float qv[HD];
    {
        float xr[HD];
        const float4* xp = (const float4*)(xbase + (size_t)tid * FEATD);
        #pragma unroll
        for (int q4 = 0; q4 < 8; ++q4) {
            float4 v = xp[q4];
            xr[q4*4+0] = v.x; xr[q4*4+1] = v.y; xr[q4*4+2] = v.z; xr[q4*4+3] = v.w;
        }
        #pragma unroll
        for (int d = 0; d < HD; ++d) {
            float s = 0.f;
            #pragma unroll
            for (int e = 0; e < HD; ++e) s += xr[e] * wq[d*HD + e];
            qv[d] = s * 0.0625f;
        }
    }

    float o[HD];
    #pragma unroll
    for (int d = 0; d < HD; ++d) o[d] = 0.f;
    float m = -1e30f, ssum = 0.f;

    for (int tile = 0; tile < 2; ++tile) {
        const int j0 = tile * 128;
        __syncthreads();
        {
            const int r = tid & 127;
            const float* W = (tid < 128) ? wk : wv;
            float xt[HD];
            const float4* xp = (const float4*)(xbase + (size_t)(j0 + r) * FEATD);
            #pragma unroll
            for (int q4 = 0; q4 < 8; ++q4) {
                float4 v = xp[q4];
                xt[q4*4+0] = v.x; xt[q4*4+1] = v.y; xt[q4*4+2] = v.z; xt[q4*4+3] = v.w;
            }
            float outr[HD];
            #pragma unroll
            for (int d = 0; d < HD; ++d) {
                float s = 0.f;
                #pragma unroll
                for (int e = 0; e < HD; ++e) s += xt[e] * W[d*HD + e];
                outr[d] = s;
            }
            float (*dst)[40] = (tid < 128) ? Ks : Vs;
            #pragma unroll
            for (int d = 0; d < HD; ++d) dst[r][d] = outr[d];
        }
        __syncthreads();

        for (int j = 0; j < 128; ++j) {
            float e = 0.f;
            #pragma unroll
            for (int dq = 0; dq < 8; ++dq) {
                float4 kq = *(const float4*)&Ks[j][dq*4];
                e += qv[dq*4+0]*kq.x + qv[dq*4+1]*kq.y
                   + qv[dq*4+2]*kq.z + qv[dq*4+3]*kq.w;
            }
            if (e > m) {
                float sc = __expf(m - e);
                ssum *= sc;
                #pragma unroll
                for (int d = 0; d < HD; ++d) o[d] *= sc;
                m = e;
            }
            float p = __expf(e - m);
            ssum += p;
            #pragma unroll
            for (int dq = 0; dq < 8; ++dq) {
                float4 vq = *(const float4*)&Vs[j][dq*4];
                o[dq*4+0] += p * vq.x; o[dq*4+1] += p * vq.y;
                o[dq*4+2] += p * vq.z; o[dq*4+3] += p * vq.w;
            }
        }
    }

    const float inv = 1.f / ssum;
    #pragma unroll
    for (int dq = 0; dq < 8; ++dq) {
        ushort4 vh, vl;
        float v0 = o[dq*4+0]*inv, v1 = o[dq*4+1]*inv,
              v2 = o[dq*4+2]*inv, v3 = o[dq*4+3]*inv;
        u16 a0 = bf16rn(v0); vh.x = a0; vl.x = bf16rn(v0 - bf2f(a0));
        u16 a1 = bf16rn(v1); vh.y = a1; vl.y = bf16rn(v1 - bf2f(a1));
        u16 a2 = bf16rn(v2); vh.z = a2; vl.z = bf16rn(v2 - bf2f(a2));
        u16 a3 = bf16rn(v3); vh.w = a3; vl.w = bf16rn(v3 - bf2f(a3));
        const size_t a = (size_t)tid*65536
                       + (size_t)(h*4 + (dq >> 1))*2048
                       + (size_t)n*8 + (dq & 1)*4;
        *(ushort4*)(attnH + a) = vh;
        *(ushort4*)(attnL + a) = vl;
    }
}

// ---------------------------------------------------------------------------
// Wc = w_hid @ w_fc; bc = w_hid @ b_fc + b_hid (verified R11-R14)
// ---------------------------------------------------------------------------
__global__ __launch_bounds__(256) void k_wcomb(
    const float* __restrict__ w_fc,  const float* __restrict__ b_fc,
    const float* __restrict__ w_hid, const float* __restrict__ b_hid,
    float* __restrict__ Wc, float* __restrict__ bc)
{
    __shared__ float wr[8][256];
    const int i0 = blockIdx.x * 8, tid = threadIdx.x;
    for (int e = tid; e < 8*256; e += 256)
        wr[e >> 8][e & 255] = w_hid[(size_t)(i0 + (e >> 8))*FEATD + (e & 255)];
    __syncthreads();
    const int j = tid;
    float acc[8] = {};
    for (int k = 0; k < FEATD; ++k) {
        const float wf = w_fc[(size_t)k*FEATD + j];
        #pragma unroll
        for (int i = 0; i < 8; ++i) acc[i] += wr[i][k] * wf;
    }
    #pragma unroll
    for (int i = 0; i < 8; ++i) Wc[(size_t)(i0 + i)*FEATD + j] = acc[i];
    if (tid < 8) {
        const int i = i0 + tid;
        float t = b_hid[i];
        for (int k = 0; k < FEATD; ++k) t += wr[tid][k] * b_fc[k];
        bc[i] = t;
    }
}

// ---------------------------------------------------------------------------
// Wx0 = W_ih[0] @ Wc; bx0 = W_ih[0] @ bc + b_ih[0] + b_hh[0] (verified)
// ---------------------------------------------------------------------------
__global__ __launch_bounds__(256) void k_wx0(
    const float* __restrict__ w_ih, const float* __restrict__ Wc,
    const float* __restrict__ bc,   const float* __restrict__ b_ih,
    const float* __restrict__ b_hh,
    float* __restrict__ Wx0, float* __restrict__ bx0)
{
    __shared__ float wr[8][512];
    const int i0 = blockIdx.x * 8, tid = threadIdx.x;
    for (int e = tid; e < 8*512; e += 256)
        wr[e >> 9][e & 511] = w_ih[(size_t)(i0 + (e >> 9))*HID + (e & 511)];
    __syncthreads();
    const int j = tid;
    float acc[8] = {};
    for (int k = 0; k < HID; ++k) {
        const float wc = Wc[(size_t)k*FEATD + j];
        #pragma unroll
        for (int i = 0; i < 8; ++i) acc[i] += wr[i][k] * wc;
    }
    #pragma unroll
    for (int i = 0; i < 8; ++i) Wx0[(size_t)(i0 + i)*FEATD + j] = acc[i];
    if (tid < 8) {
        const int i = i0 + tid;
        float t = b_ih[i] + b_hh[i];
        for (int k = 0; k < HID; ++k) t += wr[tid][k] * bc[k];
        bx0[i] = t;
    }
}

// ---------------------------------------------------------------------------
// Group barrier pieces (R14 mechanism split for overlap) + cross-group wait.
// ---------------------------------------------------------------------------
__device__ __forceinline__ void bar_arrive(int* gflags, int gidx, int step)
{
    asm volatile("s_waitcnt vmcnt(0)" ::: "memory");   // drain sc1 stores
    __syncthreads();
    if (threadIdx.x == 0)
        __hip_atomic_store(&gflags[gidx], step,
                           __ATOMIC_RELAXED, __HIP_MEMORY_SCOPE_AGENT);
}
__device__ __forceinline__ void bar_aggregate(int* gflags, int* ep, int step)
{
    if (threadIdx.x < 64) {
        const int base = (int)threadIdx.x * 2;
        for (;;) {
            int a = __hip_atomic_load(&gflags[base+0], __ATOMIC_RELAXED, __HIP_MEMORY_SCOPE_AGENT);
            int b = __hip_atomic_load(&gflags[base+1], __ATOMIC_RELAXED, __HIP_MEMORY_SCOPE_AGENT);
            if (__all(a >= step && b >= step)) break;
            __builtin_amdgcn_s_sleep(2);
        }
        if (threadIdx.x == 0)
            __hip_atomic_store(ep, step,
                               __ATOMIC_RELAXED, __HIP_MEMORY_SCOPE_AGENT);
    }
}
__device__ __forceinline__ void bar_wait(int* ep, int step)
{
    if (threadIdx.x == 0) {
        while (__hip_atomic_load(ep, __ATOMIC_RELAXED, __HIP_MEMORY_SCOPE_AGENT) < step)
            __builtin_amdgcn_s_sleep(2);
        __builtin_amdgcn_fence(__ATOMIC_ACQUIRE, "agent");
    }
    __syncthreads();
}
__device__ __forceinline__ void wait_ep(int* ep, int val)   // cross-group
{
    if (threadIdx.x == 0) {
        while (__hip_atomic_load(ep, __ATOMIC_RELAXED, __HIP_MEMORY_SCOPE_AGENT) < val)
            __builtin_amdgcn_s_sleep(2);
        __builtin_amdgcn_fence(__ATOMIC_ACQUIRE, "agent");
    }
    __syncthreads();
}

// ---------------------------------------------------------------------------
struct Geo {
    const u16* wlh; const u16* wll;   // LDS weights, fragment-major
    float* Cb;                        // LDS gate bounce [128][33]
    u16* hb;                          // LDS h-store bounce [2][128][8]
    int tid;
    int rowg, aq, bbase;
    int Mtile, col_local;
    int erow, hcl;
    int cg, mg;
    const float* bsum;
};

// Partial GEMM: acc += (split-bf16 A from src slab, CB8 layout) x
// (LDS weight slices koff..koff+NT-1). Same slice order as R5-R14.
template<int NT>
__device__ __forceinline__ void do_gemm(
    const Geo& G, const u16* __restrict__ sH, const u16* __restrict__ sL,
    int koff, f32x4& acc)
{
    uint4 pfH[DEPTH], pfL[DEPTH];
    auto ld = [&](int d, int s) {
        const size_t a = ((size_t)(s*4 + G.aq) << 11) + (size_t)G.rowg * 8;
        pfH[d] = *(const uint4*)(sH + a);
        pfL[d] = *(const uint4*)(sL + a);
    };
    constexpr int PR = (DEPTH < NT) ? DEPTH : NT;
    #pragma unroll
    for (int d = 0; d < PR; ++d) ld(d, d);
    #pragma unroll
    for (int s = 0; s < NT; ++s) {
        U8 ua, ul;
        ua.u4 = pfH[s % DEPTH];
        ul.u4 = pfL[s % DEPTH];
        if (s + DEPTH < NT) ld(s % DEPTH, s + DEPTH);
        const short8 bh = *(const short8*)(G.wlh + G.bbase + (koff + s)*512);
        const short8 bl = *(const short8*)(G.wll + G.bbase + (koff + s)*512);
        acc = __builtin_amdgcn_mfma_f32_16x16x32_bf16(ua.s8, bh, acc, 0,0,0);
        acc = __builtin_amdgcn_mfma_f32_16x16x32_bf16(ul.s8, bh, acc, 0,0,0);
        acc = __builtin_amdgcn_mfma_f32_16x16x32_bf16(ua.s8, bl, acc, 0,0,0);
    }
}

// Epilogue (verified R14): Cb bounce -> gates -> hb bounce -> 256x16B sc1.
__device__ __forceinline__ void epi(
    const Geo& G, const f32x4& acc, float& cr,
    u16* __restrict__ dH, u16* __restrict__ dL)
{
    {
        const int crow = G.Mtile*16 + G.aq*4;
        #pragma unroll
        for (int r = 0; r < 4; ++r)
            G.Cb[(crow + r)*33 + G.col_local] = acc[r];
    }
    __syncthreads();
    {
        float g4[4];
        #pragma unroll
        for (int g = 0; g < 4; ++g) g4[g] = G.Cb[G.erow*33 + g*8 + G.hcl] + G.bsum[g];
        const float gi = sigm(g4[0]), gf = sigm(g4[1]);
        const float gg = tanhfast(g4[2]), go = sigm(g4[3]);
        cr = gf*cr + gi*gg;
        const float h = go * tanhfast(cr);
        const u16 hh = bf16rn(h);
        const u16 hl = bf16rn(h - bf2f(hh));
        G.hb[G.erow*8 + G.hcl]        = hh;
        G.hb[1024 + G.erow*8 + G.hcl] = hl;
    }
    __syncthreads();
    if (G.tid < 256) {
        const int row = G.tid & 127, pl = G.tid >> 7;
        const u32x4 v = *(const u32x4*)&G.hb[pl*1024 + row*8];
        u16* dst = pl ? dL : dH;
        st16_dev(dst + ((size_t)G.cg << 11) + (size_t)(G.mg*128 + row)*8, v);
    }
}

// ---------------------------------------------------------------------------
// Persistent split-barrier LSTM. 256 blocks x 1024 threads (4 waves/SIMD).
// L1 group: blocks 0..127 (aggregator 0, epoch l1ep). L0 group: 128..255
// (aggregator 128, epoch l0ep). h rings 4-deep. Per step, only the
// RECURRENT 16 slices + epilogue + 128-block barrier are serial; the
// non-recurrent partial (Wih1*h0 / Wx0*attn) and L0's projection run in the
// arrive->poll overlap window. Accumulation order identical to R5-R14.
// ---------------------------------------------------------------------------
__global__ __launch_bounds__(THR, 1) void k_lstm(
    const u16* __restrict__ attnH, const u16* __restrict__ attnL,
    const float* __restrict__ Wx0, const float* __restrict__ bx0,
    u16* __restrict__ h0h, u16* __restrict__ h0l,
    u16* __restrict__ h1h, u16* __restrict__ h1l,
    const float* __restrict__ w_ih, const float* __restrict__ w_hh,
    const float* __restrict__ b_ih, const float* __restrict__ b_hh,
    const float* __restrict__ w_out, const float* __restrict__ b_out,
    float* __restrict__ out, int* __restrict__ fl)
{
    extern __shared__ char smem[];
    int* l1flags = fl;
    int* l0flags = fl + 128;
    int* l1ep    = fl + 256;
    int* l0ep    = fl + 320;

    const int tid  = threadIdx.x;
    const int bx   = blockIdx.x;
    const bool lay1 = (bx < 128);
    const int idx  = lay1 ? bx : bx - 128;
    const int cg   = idx >> 1;
    const int mg   = idx & 1;
    const int KW   = lay1 ? 1024 : 768;
    const int NS   = KW >> 5;

    u16*   wlh = (u16*)smem;
    u16*   wll = wlh + 2*NS*512;
    float* Cb  = (float*)(smem + 132096);
    u16*   hb  = (u16*)(smem + 148992);

    const int wid = tid >> 6, l = tid & 63;
    const int Mtile = wid & 7, Ntile = wid >> 3;
    const int lr = l & 15, aq = l >> 4;

    Geo G;
    G.wlh = wlh; G.wll = wll; G.Cb = Cb; G.hb = hb; G.tid = tid;
    G.rowg = mg*128 + Mtile*16 + lr;
    G.aq = aq;
    G.Mtile = Mtile;
    G.col_local = Ntile*16 + lr;
    G.bbase = Ntile*NS*512 + l*8;
    G.erow = tid & 127; G.hcl = tid >> 7;
    G.cg = cg; G.mg = mg;

    // ---- stage weights (fragment-major split bf16, verified R10-R14)
    for (int c = 0; c < 32; ++c) {
        const int grow = (c >> 3)*HID + cg*8 + (c & 7);
        const float* src0; const float* src1; int klen0;
        if (lay1) {
            src0 = w_ih + (size_t)GATES*HID + (size_t)grow*HID; klen0 = 512;
            src1 = w_hh + (size_t)GATES*HID + (size_t)grow*HID;
        } else {
            src0 = Wx0 + (size_t)grow*FEATD;                    klen0 = 256;
            src1 = w_hh + (size_t)grow*HID;
        }
        const int fb = (c >> 4)*NS*512 + (c & 15)*8;
        for (int k = tid; k < KW; k += THR) {
            float f = (k < klen0) ? src0[k] : src1[k - klen0];
            u16 hi = bf16rn(f);
            const int fidx = fb + (k >> 5)*512 + (((k >> 3) & 3) << 7) + (k & 7);
            wlh[fidx] = hi;
            wll[fidx] = bf16rn(f - bf2f(hi));
        }
    }

    float bsum[4];
    #pragma unroll
    for (int g = 0; g < 4; ++g) {
        const int gidx = g*HID + cg*8 + G.hcl;
        bsum[g] = lay1 ? (b_ih[GATES + gidx] + b_hh[GATES + gidx]) : bx0[gidx];
    }
    G.bsum = bsum;
    float cr = 0.f;
    __syncthreads();

    auto proj = [&](const u16* hH, const u16* hL, int tout) {
        if (tid < 256) {
            const int r = tid >> 7, j = (tid >> 4) & 7, ks = tid & 15;
            const int n = 2*idx + r;
            float s = 0.f;
            #pragma unroll
            for (int kk = 0; kk < 32; ++kk) {
                const int k = ks*32 + kk;
                const size_t a = (size_t)(k >> 3)*2048 + (size_t)n*8 + (k & 7);
                float hv = bf2f(hH[a]) + bf2f(hL[a]);
                hv = hv > 0.f ? hv : 0.f;
                s += hv * w_out[(size_t)j*HID + k];
            }
            s += __shfl_xor(s, 1); s += __shfl_xor(s, 2);
            s += __shfl_xor(s, 4); s += __shfl_xor(s, 8);
            if (ks == 0)
                out[(size_t)n*(TOUT*NHEADS) + (size_t)tout*NHEADS + j] = s + b_out[j];
        }
    };

    f32x4 acc = {0.f, 0.f, 0.f, 0.f};

    if (lay1) {
        // ================= LAYER-1 group =================
        wait_ep(l0ep, 1);
        do_gemm<16>(G, h0h, h0l, 0, acc);                  // P(0) = Wih1*h0(0)
        for (int t = 0; t <= 254; ++t) {
            if (t >= 1)
                do_gemm<16>(G, h1h + (size_t)((t-1)&3)*BH,
                               h1l + (size_t)((t-1)&3)*BH, 16, acc);
            epi(G, acc, cr, h1h + (size_t)(t&3)*BH, h1l + (size_t)(t&3)*BH);
            bar_arrive(l1flags, idx, t + 1);
            if (bx == 0) bar_aggregate(l1flags, l1ep, t + 1);
            acc = (f32x4){0.f, 0.f, 0.f, 0.f};
            if (t < 254) {                                  // overlap: P(t+1)
                wait_ep(l0ep, t + 2);
                do_gemm<16>(G, h0h + (size_t)((t+1)&3)*BH,
                               h0l + (size_t)((t+1)&3)*BH, 0, acc);
            }
            bar_wait(l1ep, t + 1);
        }
    } else {
        // ================= LAYER-0 group =================
        do_gemm<8>(G, attnH, attnL, 0, acc);                // s=0: Wx0*attn(0)
        epi(G, acc, cr, h0h, h0l);
        bar_arrive(l0flags, idx, 1);
        if (bx == 128) bar_aggregate(l0flags, l0ep, 1);
        acc = (f32x4){0.f, 0.f, 0.f, 0.f};
        do_gemm<8>(G, attnH + 65536, attnL + 65536, 0, acc); // P(1)
        bar_wait(l0ep, 1);

        for (int s = 1; s <= 254; ++s) {
            if (s >= 2) wait_ep(l1ep, s - 1);               // ring + proj gate
            do_gemm<16>(G, h0h + (size_t)((s-1)&3)*BH,
                           h0l + (size_t)((s-1)&3)*BH, 8, acc);
            epi(G, acc, cr, h0h + (size_t)(s&3)*BH, h0l + (size_t)(s&3)*BH);
            bar_arrive(l0flags, idx, s + 1);
            if (bx == 128) bar_aggregate(l0flags, l0ep, s + 1);
            acc = (f32x4){0.f, 0.f, 0.f, 0.f};
            if (s < 254)                                    // overlap: P(s+1)
                do_gemm<8>(G, attnH + (size_t)(s+1)*65536,
                              attnL + (size_t)(s+1)*65536, 0, acc);
            if (s >= 2)                                     // overlap: proj
                proj(h1h + (size_t)((s-2)&3)*BH,
                     h1l + (size_t)((s-2)&3)*BH, s - 2);
            bar_wait(l0ep, s + 1);
        }
        // tail projections
        wait_ep(l1ep, 255);
        proj(h1h + (size_t)(253&3)*BH, h1l + (size_t)(253&3)*BH, 253);
        proj(h1h + (size_t)(254&3)*BH, h1l + (size_t)(254&3)*BH, 254);
    }
}

// ---------------------------------------------------------------------------
extern "C" void kernel_launch(void* const* d_in, const int* in_sizes, int n_in,
                              void* d_out, int out_size, void* d_ws, size_t ws_size,
                              hipStream_t stream)
{
    (void)in_sizes; (void)n_in; (void)out_size; (void)ws_size;
    const float* x     = (const float*)d_in[0];
    const float* wq    = (const float*)d_in[1];
    const float* wk    = (const float*)d_in[2];
    const float* wv    = (const float*)d_in[3];
    const float* w_fc  = (const float*)d_in[4];
    const float* b_fc  = (const float*)d_in[5];
    const float* w_hid = (const float*)d_in[6];
    const float* b_hid = (const float*)d_in[7];
    const float* w_ih  = (const float*)d_in[8];
    const float* w_hh  = (const float*)d_in[9];
    const float* b_ih  = (const float*)d_in[10];
    const float* b_hh  = (const float*)d_in[11];
    const float* w_out = (const float*)d_in[12];
    const float* b_out = (const float*)d_in[13];

    float* ws = (float*)d_ws;
    size_t off = 0;
    u16* attnH = (u16*)(ws + off); off += (size_t)SEQT*BATCH*FEATD/2;
    u16* attnL = (u16*)(ws + off); off += (size_t)SEQT*BATCH*FEATD/2;
    float* Wc  = ws + off; off += (size_t)HID*FEATD;
    float* bc  = ws + off; off += HID;
    float* Wx0 = ws + off; off += (size_t)GATES*FEATD;
    float* bx0 = ws + off; off += GATES;
    u16* h0h = (u16*)(ws + off); off += 2*BH;   // 4 slabs of BH halves
    u16* h0l = (u16*)(ws + off); off += 2*BH;
    u16* h1h = (u16*)(ws + off); off += 2*BH;
    u16* h1l = (u16*)(ws + off); off += 2*BH;
    int* fl  = (int*)(ws + off); off += 512;    // flags + epochs

    (void)hipMemsetAsync(fl, 0, 512*sizeof(int), stream);

    k_attn  <<<dim3(BATCH*NHEADS), dim3(256), 0, stream>>>(x, wq, wk, wv, attnH, attnL);
    k_wcomb <<<dim3(64),           dim3(256), 0, stream>>>(w_fc, b_fc, w_hid, b_hid, Wc, bc);
    k_wx0   <<<dim3(256),          dim3(256), 0, stream>>>(w_ih, Wc, bc, b_ih, b_hh, Wx0, bx0);

    const int shmem = 132096 + 128*33*4 + 4096;   // weights + Cb + h bounce
    (void)hipFuncSetAttribute(reinterpret_cast<const void*>(k_lstm),
                              hipFuncAttributeMaxDynamicSharedMemorySize, shmem);
    k_lstm <<<dim3(NBLK), dim3(THR), (size_t)shmem, stream>>>(
        attnH, attnL, Wx0, bx0, h0h, h0l, h1h, h1l,
        w_ih, w_hh, b_ih, b_hh, w_out, b_out, (float*)d_out, fl);
}

// Round 16
// 4842.662 us; speedup vs baseline: 3.8832x; 1.3332x over previous
//
#include <hip/hip_runtime.h>
#include <math.h>

// Problem constants
#define BATCH  256
#define SEQT   256
#define FEATD  256
#define NHEADS 8
#define HD     32
#define HID    512
#define GATES  2048
#define BH     (BATCH*HID)       // halves per h plane slab
#define TOUT   (SEQT-1)
#define NBLK   256
#define THR    1024
#define DEPTH  8                 // prefetch depth (slices), hi-plane only

typedef __attribute__((ext_vector_type(8))) short short8;
typedef __attribute__((ext_vector_type(4))) float f32x4;
typedef __attribute__((ext_vector_type(4))) unsigned int u32x4;
typedef unsigned short u16;

union U8 { uint4 u4; short8 s8; };

__device__ __forceinline__ float sigm(float x)     { return 1.f / (1.f + __expf(-x)); }
__device__ __forceinline__ float tanhfast(float x) { return 1.f - 2.f / (1.f + __expf(2.f * x)); }

__device__ __forceinline__ u16 bf16rn(float f) {
    union { float f; unsigned u; } v; v.f = f;
    unsigned r = v.u + 0x7fffu + ((v.u >> 16) & 1u);
    return (u16)(r >> 16);
}
__device__ __forceinline__ float bf2f(u16 h) {
    union { float f; unsigned u; } v; v.u = ((unsigned)h) << 16; return v.f;
}

// Device-scope (sc1) 16B store (verified R14/R15).
__device__ __forceinline__ void st16_dev(void* p, u32x4 v) {
    unsigned long long a = (unsigned long long)p;
    asm volatile("global_store_dwordx4 %0, %1, off sc1"
                 :: "v"(a), "v"(v) : "memory");
}

// ---------------------------------------------------------------------------
// Fused per-(n,h) attention (math verified rounds 2-15). Output T-major CB8,
// SINGLE bf16 plane: attn[t][cb8=f/8][n][8].
// ---------------------------------------------------------------------------
__global__ __launch_bounds__(256) void k_attn(
    const float* __restrict__ x,  const float* __restrict__ wq,
    const float* __restrict__ wk, const float* __restrict__ wv,
    u16* __restrict__ attnH)
{
    __shared__ float Ks[128][40];
    __shared__ float Vs[128][40];

    const int nb  = blockIdx.x;
    const int n   = nb >> 3, h = nb & 7;
    const int tid = threadIdx.x;
    const float* xbase = x + ((size_t)n * SEQT) * FEATD + h * HD;

    float qv[HD];
    {
        float xr[HD];
        const float4* xp = (const float4*)(xbase + (size_t)tid * FEATD);
        #pragma unroll
        for (int q4 = 0; q4 < 8; ++q4) {
            float4 v = xp[q4];
            xr[q4*4+0] = v.x; xr[q4*4+1] = v.y; xr[q4*4+2] = v.z; xr[q4*4+3] = v.w;
        }
        #pragma unroll
        for (int d = 0; d < HD; ++d) {
            float s = 0.f;
            #pragma unroll
            for (int e = 0; e < HD; ++e) s += xr[e] * wq[d*HD + e];
            qv[d] = s * 0.0625f;
        }
    }

    float o[HD];
    #pragma unroll
    for (int d = 0; d < HD; ++d) o[d] = 0.f;
    float m = -1e30f, ssum = 0.f;

    for (int tile = 0; tile < 2; ++tile) {
        const int j0 = tile * 128;
        __syncthreads();
        {
            const int r = tid & 127;
            const float* W = (tid < 128) ? wk : wv;
            float xt[HD];
            const float4* xp = (const float4*)(xbase + (size_t)(j0 + r) * FEATD);
            #pragma unroll
            for (int q4 = 0; q4 < 8; ++q4) {
                float4 v = xp[q4];
                xt[q4*4+0] = v.x; xt[q4*4+1] = v.y; xt[q4*4+2] = v.z; xt[q4*4+3] = v.w;
            }
            float outr[HD];
            #pragma unroll
            for (int d = 0; d < HD; ++d) {
                float s = 0.f;
                #pragma unroll
                for (int e = 0; e < HD; ++e) s += xt[e] * W[d*HD + e];
                outr[d] = s;
            }
            float (*dst)[40] = (tid < 128) ? Ks : Vs;
            #pragma unroll
            for (int d = 0; d < HD; ++d) dst[r][d] = outr[d];
        }
        __syncthreads();

        for (int j = 0; j < 128; ++j) {
            float e = 0.f;
            #pragma unroll
            for (int dq = 0; dq < 8; ++dq) {
                float4 kq = *(const float4*)&Ks[j][dq*4];
                e += qv[dq*4+0]*kq.x + qv[dq*4+1]*kq.y
                   + qv[dq*4+2]*kq.z + qv[dq*4+3]*kq.w;
            }
            if (e > m) {
                float sc = __expf(m - e);
                ssum *= sc;
                #pragma unroll
                for (int d = 0; d < HD; ++d) o[d] *= sc;
                m = e;
            }
            float p = __expf(e - m);
            ssum += p;
            #pragma unroll
            for (int dq = 0; dq < 8; ++dq) {
                float4 vq = *(const float4*)&Vs[j][dq*4];
                o[dq*4+0] += p * vq.x; o[dq*4+1] += p * vq.y;
                o[dq*4+2] += p * vq.z; o[dq*4+3] += p * vq.w;
            }
        }
    }

    const float inv = 1.f / ssum;
    #pragma unroll
    for (int dq = 0; dq < 8; ++dq) {
        ushort4 vh;
        vh.x = bf16rn(o[dq*4+0]*inv);
        vh.y = bf16rn(o[dq*4+1]*inv);
        vh.z = bf16rn(o[dq*4+2]*inv);
        vh.w = bf16rn(o[dq*4+3]*inv);
        const size_t a = (size_t)tid*65536
                       + (size_t)(h*4 + (dq >> 1))*2048
                       + (size_t)n*8 + (dq & 1)*4;
        *(ushort4*)(attnH + a) = vh;
    }
}

// ---------------------------------------------------------------------------
// Wc = w_hid @ w_fc; bc = w_hid @ b_fc + b_hid (verified R11-R15)
// ---------------------------------------------------------------------------
__global__ __launch_bounds__(256) void k_wcomb(
    const float* __restrict__ w_fc,  const float* __restrict__ b_fc,
    const float* __restrict__ w_hid, const float* __restrict__ b_hid,
    float* __restrict__ Wc, float* __restrict__ bc)
{
    __shared__ float wr[8][256];
    const int i0 = blockIdx.x * 8, tid = threadIdx.x;
    for (int e = tid; e < 8*256; e += 256)
        wr[e >> 8][e & 255] = w_hid[(size_t)(i0 + (e >> 8))*FEATD + (e & 255)];
    __syncthreads();
    const int j = tid;
    float acc[8] = {};
    for (int k = 0; k < FEATD; ++k) {
        const float wf = w_fc[(size_t)k*FEATD + j];
        #pragma unroll
        for (int i = 0; i < 8; ++i) acc[i] += wr[i][k] * wf;
    }
    #pragma unroll
    for (int i = 0; i < 8; ++i) Wc[(size_t)(i0 + i)*FEATD + j] = acc[i];
    if (tid < 8) {
        const int i = i0 + tid;
        float t = b_hid[i];
        for (int k = 0; k < FEATD; ++k) t += wr[tid][k] * b_fc[k];
        bc[i] = t;
    }
}

// ---------------------------------------------------------------------------
// Wx0 = W_ih[0] @ Wc; bx0 = W_ih[0] @ bc + b_ih[0] + b_hh[0] (verified)
// ---------------------------------------------------------------------------
__global__ __launch_bounds__(256) void k_wx0(
    const float* __restrict__ w_ih, const float* __restrict__ Wc,
    const float* __restrict__ bc,   const float* __restrict__ b_ih,
    const float* __restrict__ b_hh,
    float* __restrict__ Wx0, float* __restrict__ bx0)
{
    __shared__ float wr[8][512];
    const int i0 = blockIdx.x * 8, tid = threadIdx.x;
    for (int e = tid; e < 8*512; e += 256)
        wr[e >> 9][e & 511] = w_ih[(size_t)(i0 + (e >> 9))*HID + (e & 511)];
    __syncthreads();
    const int j = tid;
    float acc[8] = {};
    for (int k = 0; k < HID; ++k) {
        const float wc = Wc[(size_t)k*FEATD + j];
        #pragma unroll
        for (int i = 0; i < 8; ++i) acc[i] += wr[i][k] * wc;
    }
    #pragma unroll
    for (int i = 0; i < 8; ++i) Wx0[(size_t)(i0 + i)*FEATD + j] = acc[i];
    if (tid < 8) {
        const int i = i0 + tid;
        float t = b_ih[i] + b_hh[i];
        for (int k = 0; k < HID; ++k) t += wr[tid][k] * bc[k];
        bx0[i] = t;
    }
}

// ---------------------------------------------------------------------------
// Group barrier pieces + cross-group wait (verified R15).
// ---------------------------------------------------------------------------
__device__ __forceinline__ void bar_arrive(int* gflags, int gidx, int step)
{
    asm volatile("s_waitcnt vmcnt(0)" ::: "memory");   // drain sc1 stores
    __syncthreads();
    if (threadIdx.x == 0)
        __hip_atomic_store(&gflags[gidx], step,
                           __ATOMIC_RELAXED, __HIP_MEMORY_SCOPE_AGENT);
}
__device__ __forceinline__ void bar_aggregate(int* gflags, int* ep, int step)
{
    if (threadIdx.x < 64) {
        const int base = (int)threadIdx.x * 2;
        for (;;) {
            int a = __hip_atomic_load(&gflags[base+0], __ATOMIC_RELAXED, __HIP_MEMORY_SCOPE_AGENT);
            int b = __hip_atomic_load(&gflags[base+1], __ATOMIC_RELAXED, __HIP_MEMORY_SCOPE_AGENT);
            if (__all(a >= step && b >= step)) break;
            __builtin_amdgcn_s_sleep(2);
        }
        if (threadIdx.x == 0)
            __hip_atomic_store(ep, step,
                               __ATOMIC_RELAXED, __HIP_MEMORY_SCOPE_AGENT);
    }
}
__device__ __forceinline__ void bar_wait(int* ep, int step)
{
    if (threadIdx.x == 0) {
        while (__hip_atomic_load(ep, __ATOMIC_RELAXED, __HIP_MEMORY_SCOPE_AGENT) < step)
            __builtin_amdgcn_s_sleep(2);
        __builtin_amdgcn_fence(__ATOMIC_ACQUIRE, "agent");
    }
    __syncthreads();
}
__device__ __forceinline__ void wait_ep(int* ep, int val)
{
    if (threadIdx.x == 0) {
        while (__hip_atomic_load(ep, __ATOMIC_RELAXED, __HIP_MEMORY_SCOPE_AGENT) < val)
            __builtin_amdgcn_s_sleep(2);
        __builtin_amdgcn_fence(__ATOMIC_ACQUIRE, "agent");
    }
    __syncthreads();
}

// ---------------------------------------------------------------------------
struct Geo {
    const u16* wlh; const u16* wll;   // LDS weights, fragment-major (hi+lo)
    float* Cb;                        // LDS gate bounce [128][33]
    u16* hb;                          // LDS h-store bounce [128][8]
    int tid;
    int rowg, aq, bbase;
    int Mtile, col_local;
    int erow, hcl;
    int cg, mg;
    const float* bsum;
};

// Partial GEMM, 2-term split: acc += ah*(wh + wl). A = single bf16 plane.
// Slice order identical to R5-R15 (source-0 slices then source-1).
template<int NT>
__device__ __forceinline__ void do_gemm(
    const Geo& G, const u16* __restrict__ sH, int koff, f32x4& acc)
{
    uint4 pfH[DEPTH];
    auto ld = [&](int d, int s) {
        const size_t a = ((size_t)(s*4 + G.aq) << 11) + (size_t)G.rowg * 8;
        pfH[d] = *(const uint4*)(sH + a);
    };
    constexpr int PR = (DEPTH < NT) ? DEPTH : NT;
    #pragma unroll
    for (int d = 0; d < PR; ++d) ld(d, d);
    #pragma unroll
    for (int s = 0; s < NT; ++s) {
        U8 ua;
        ua.u4 = pfH[s % DEPTH];
        if (s + DEPTH < NT) ld(s % DEPTH, s + DEPTH);
        const short8 bh = *(const short8*)(G.wlh + G.bbase + (koff + s)*512);
        const short8 bl = *(const short8*)(G.wll + G.bbase + (koff + s)*512);
        acc = __builtin_amdgcn_mfma_f32_16x16x32_bf16(ua.s8, bh, acc, 0,0,0);
        acc = __builtin_amdgcn_mfma_f32_16x16x32_bf16(ua.s8, bl, acc, 0,0,0);
    }
}

// Epilogue: Cb bounce -> gates -> hb bounce -> 128 x 16B sc1 stores.
__device__ __forceinline__ void epi(
    const Geo& G, const f32x4& acc, float& cr, u16* __restrict__ dH)
{
    {
        const int crow = G.Mtile*16 + G.aq*4;
        #pragma unroll
        for (int r = 0; r < 4; ++r)
            G.Cb[(crow + r)*33 + G.col_local] = acc[r];
    }
    __syncthreads();
    {
        float g4[4];
        #pragma unroll
        for (int g = 0; g < 4; ++g) g4[g] = G.Cb[G.erow*33 + g*8 + G.hcl] + G.bsum[g];
        const float gi = sigm(g4[0]), gf = sigm(g4[1]);
        const float gg = tanhfast(g4[2]), go = sigm(g4[3]);
        cr = gf*cr + gi*gg;
        const float h = go * tanhfast(cr);
        G.hb[G.erow*8 + G.hcl] = bf16rn(h);
    }
    __syncthreads();
    if (G.tid < 128) {
        const int row = G.tid;
        const u32x4 v = *(const u32x4*)&G.hb[row*8];
        st16_dev(dH + ((size_t)G.cg << 11) + (size_t)(G.mg*128 + row)*8, v);
    }
}

// ---------------------------------------------------------------------------
// Persistent split-barrier LSTM (structure verified R15), single-plane A.
// L1 group: blocks 0..127; L0 group: 128..255. h rings 4-deep, bf16 hi only.
// ---------------------------------------------------------------------------
__global__ __launch_bounds__(THR, 1) void k_lstm(
    const u16* __restrict__ attnH,
    const float* __restrict__ Wx0, const float* __restrict__ bx0,
    u16* __restrict__ h0h, u16* __restrict__ h1h,
    const float* __restrict__ w_ih, const float* __restrict__ w_hh,
    const float* __restrict__ b_ih, const float* __restrict__ b_hh,
    const float* __restrict__ w_out, const float* __restrict__ b_out,
    float* __restrict__ out, int* __restrict__ fl)
{
    extern __shared__ char smem[];
    int* l1flags = fl;
    int* l0flags = fl + 128;
    int* l1ep    = fl + 256;
    int* l0ep    = fl + 320;

    const int tid  = threadIdx.x;
    const int bx   = blockIdx.x;
    const bool lay1 = (bx < 128);
    const int idx  = lay1 ? bx : bx - 128;
    const int cg   = idx >> 1;
    const int mg   = idx & 1;
    const int KW   = lay1 ? 1024 : 768;
    const int NS   = KW >> 5;

    u16*   wlh = (u16*)smem;
    u16*   wll = wlh + 2*NS*512;
    float* Cb  = (float*)(smem + 132096);
    u16*   hb  = (u16*)(smem + 148992);

    const int wid = tid >> 6, l = tid & 63;
    const int Mtile = wid & 7, Ntile = wid >> 3;
    const int lr = l & 15, aq = l >> 4;

    Geo G;
    G.wlh = wlh; G.wll = wll; G.Cb = Cb; G.hb = hb; G.tid = tid;
    G.rowg = mg*128 + Mtile*16 + lr;
    G.aq = aq;
    G.Mtile = Mtile;
    G.col_local = Ntile*16 + lr;
    G.bbase = Ntile*NS*512 + l*8;
    G.erow = tid & 127; G.hcl = tid >> 7;
    G.cg = cg; G.mg = mg;

    // ---- stage weights (fragment-major split bf16, verified R10-R15)
    for (int c = 0; c < 32; ++c) {
        const int grow = (c >> 3)*HID + cg*8 + (c & 7);
        const float* src0; const float* src1; int klen0;
        if (lay1) {
            src0 = w_ih + (size_t)GATES*HID + (size_t)grow*HID; klen0 = 512;
            src1 = w_hh + (size_t)GATES*HID + (size_t)grow*HID;
        } else {
            src0 = Wx0 + (size_t)grow*FEATD;                    klen0 = 256;
            src1 = w_hh + (size_t)grow*HID;
        }
        const int fb = (c >> 4)*NS*512 + (c & 15)*8;
        for (int k = tid; k < KW; k += THR) {
            float f = (k < klen0) ? src0[k] : src1[k - klen0];
            u16 hi = bf16rn(f);
            const int fidx = fb + (k >> 5)*512 + (((k >> 3) & 3) << 7) + (k & 7);
            wlh[fidx] = hi;
            wll[fidx] = bf16rn(f - bf2f(hi));
        }
    }

    float bsum[4];
    #pragma unroll
    for (int g = 0; g < 4; ++g) {
        const int gidx = g*HID + cg*8 + G.hcl;
        bsum[g] = lay1 ? (b_ih[GATES + gidx] + b_hh[GATES + gidx]) : bx0[gidx];
    }
    G.bsum = bsum;
    float cr = 0.f;
    __syncthreads();

    auto proj = [&](const u16* hH, int tout) {
        if (tid < 256) {
            const int r = tid >> 7, j = (tid >> 4) & 7, ks = tid & 15;
            const int n = 2*idx + r;
            float s = 0.f;
            #pragma unroll
            for (int kk = 0; kk < 32; ++kk) {
                const int k = ks*32 + kk;
                const size_t a = (size_t)(k >> 3)*2048 + (size_t)n*8 + (k & 7);
                float hv = bf2f(hH[a]);
                hv = hv > 0.f ? hv : 0.f;
                s += hv * w_out[(size_t)j*HID + k];
            }
            s += __shfl_xor(s, 1); s += __shfl_xor(s, 2);
            s += __shfl_xor(s, 4); s += __shfl_xor(s, 8);
            if (ks == 0)
                out[(size_t)n*(TOUT*NHEADS) + (size_t)tout*NHEADS + j] = s + b_out[j];
        }
    };

    f32x4 acc = {0.f, 0.f, 0.f, 0.f};

    if (lay1) {
        // ================= LAYER-1 group =================
        wait_ep(l0ep, 1);
        do_gemm<16>(G, h0h, 0, acc);                       // P(0) = Wih1*h0(0)
        for (int t = 0; t <= 254; ++t) {
            if (t >= 1)
                do_gemm<16>(G, h1h + (size_t)((t-1)&3)*BH, 16, acc);
            epi(G, acc, cr, h1h + (size_t)(t&3)*BH);
            bar_arrive(l1flags, idx, t + 1);
            if (bx == 0) bar_aggregate(l1flags, l1ep, t + 1);
            acc = (f32x4){0.f, 0.f, 0.f, 0.f};
            if (t < 254) {                                  // overlap: P(t+1)
                wait_ep(l0ep, t + 2);
                do_gemm<16>(G, h0h + (size_t)((t+1)&3)*BH, 0, acc);
            }
            bar_wait(l1ep, t + 1);
        }
    } else {
        // ================= LAYER-0 group =================
        do_gemm<8>(G, attnH, 0, acc);                       // s=0: Wx0*attn(0)
        epi(G, acc, cr, h0h);
        bar_arrive(l0flags, idx, 1);
        if (bx == 128) bar_aggregate(l0flags, l0ep, 1);
        acc = (f32x4){0.f, 0.f, 0.f, 0.f};
        do_gemm<8>(G, attnH + 65536, 0, acc);               // P(1)
        bar_wait(l0ep, 1);

        for (int s = 1; s <= 254; ++s) {
            if (s >= 2) wait_ep(l1ep, s - 1);               // ring + proj gate
            do_gemm<16>(G, h0h + (size_t)((s-1)&3)*BH, 8, acc);
            epi(G, acc, cr, h0h + (size_t)(s&3)*BH);
            bar_arrive(l0flags, idx, s + 1);
            if (bx == 128) bar_aggregate(l0flags, l0ep, s + 1);
            acc = (f32x4){0.f, 0.f, 0.f, 0.f};
            if (s < 254)                                    // overlap: P(s+1)
                do_gemm<8>(G, attnH + (size_t)(s+1)*65536, 0, acc);
            if (s >= 2)                                     // overlap: proj
                proj(h1h + (size_t)((s-2)&3)*BH, s - 2);
            bar_wait(l0ep, s + 1);
        }
        // tail projections
        wait_ep(l1ep, 255);
        proj(h1h + (size_t)(253&3)*BH, 253);
        proj(h1h + (size_t)(254&3)*BH, 254);
    }
}

// ---------------------------------------------------------------------------
extern "C" void kernel_launch(void* const* d_in, const int* in_sizes, int n_in,
                              void* d_out, int out_size, void* d_ws, size_t ws_size,
                              hipStream_t stream)
{
    (void)in_sizes; (void)n_in; (void)out_size; (void)ws_size;
    const float* x     = (const float*)d_in[0];
    const float* wq    = (const float*)d_in[1];
    const float* wk    = (const float*)d_in[2];
    const float* wv    = (const float*)d_in[3];
    const float* w_fc  = (const float*)d_in[4];
    const float* b_fc  = (const float*)d_in[5];
    const float* w_hid = (const float*)d_in[6];
    const float* b_hid = (const float*)d_in[7];
    const float* w_ih  = (const float*)d_in[8];
    const float* w_hh  = (const float*)d_in[9];
    const float* b_ih  = (const float*)d_in[10];
    const float* b_hh  = (const float*)d_in[11];
    const float* w_out = (const float*)d_in[12];
    const float* b_out = (const float*)d_in[13];

    float* ws = (float*)d_ws;
    size_t off = 0;
    u16* attnH = (u16*)(ws + off); off += (size_t)SEQT*BATCH*FEATD/2;
    float* Wc  = ws + off; off += (size_t)HID*FEATD;
    float* bc  = ws + off; off += HID;
    float* Wx0 = ws + off; off += (size_t)GATES*FEATD;
    float* bx0 = ws + off; off += GATES;
    u16* h0h = (u16*)(ws + off); off += 2*BH;   // 4 slabs of BH halves
    u16* h1h = (u16*)(ws + off); off += 2*BH;
    int* fl  = (int*)(ws + off); off += 512;    // flags + epochs

    (void)hipMemsetAsync(fl, 0, 512*sizeof(int), stream);

    k_attn  <<<dim3(BATCH*NHEADS), dim3(256), 0, stream>>>(x, wq, wk, wv, attnH);
    k_wcomb <<<dim3(64),           dim3(256), 0, stream>>>(w_fc, b_fc, w_hid, b_hid, Wc, bc);
    k_wx0   <<<dim3(256),          dim3(256), 0, stream>>>(w_ih, Wc, bc, b_ih, b_hh, Wx0, bx0);

    const int shmem = 132096 + 128*33*4 + 2048;   // weights + Cb + h bounce
    (void)hipFuncSetAttribute(reinterpret_cast<const void*>(k_lstm),
                              hipFuncAttributeMaxDynamicSharedMemorySize, shmem);
    k_lstm <<<dim3(NBLK), dim3(THR), (size_t)shmem, stream>>>(
        attnH, Wx0, bx0, h0h, h1h,
        w_ih, w_hh, b_ih, b_hh, w_out, b_out, (float*)d_out, fl);
}

// Round 17
// 4132.032 us; speedup vs baseline: 4.5510x; 1.1720x over previous
//
#include <hip/hip_runtime.h>
#include <math.h>

// Problem constants
#define BATCH  256
#define SEQT   256
#define FEATD  256
#define NHEADS 8
#define HD     32
#define HID    512
#define GATES  2048
#define BH     (BATCH*HID)       // halves per h plane slab
#define TOUT   (SEQT-1)
#define NBLK   256
#define THR    1024
#define DEPTH  8                 // prefetch depth (slices), hi-plane only
#define ACH    512               // attention chunk (nb per pass)

typedef __attribute__((ext_vector_type(8))) short short8;
typedef __attribute__((ext_vector_type(4))) float f32x4;
typedef __attribute__((ext_vector_type(4))) unsigned int u32x4;
typedef unsigned short u16;

union U8 { uint4 u4; short8 s8; };

__device__ __forceinline__ float sigm(float x)     { return 1.f / (1.f + __expf(-x)); }
__device__ __forceinline__ float tanhfast(float x) { return 1.f - 2.f / (1.f + __expf(2.f * x)); }

__device__ __forceinline__ u16 bf16rn(float f) {
    union { float f; unsigned u; } v; v.f = f;
    unsigned r = v.u + 0x7fffu + ((v.u >> 16) & 1u);
    return (u16)(r >> 16);
}
__device__ __forceinline__ float bf2f(u16 h) {
    union { float f; unsigned u; } v; v.u = ((unsigned)h) << 16; return v.f;
}

// Device-scope (sc1) 16B store (verified R14-R16).
__device__ __forceinline__ void st16_dev(void* p, u32x4 v) {
    unsigned long long a = (unsigned long long)p;
    asm volatile("global_store_dwordx4 %0, %1, off sc1"
                 :: "v"(a), "v"(v) : "memory");
}

// ---------------------------------------------------------------------------
// K/V projections for one chunk of (n,h) pairs -> global fp32 rows.
// Same dot order as the verified R2-R16 staging loop.
// ---------------------------------------------------------------------------
__global__ __launch_bounds__(256) void k_qkv(
    const float* __restrict__ x,
    const float* __restrict__ wk, const float* __restrict__ wv,
    float* __restrict__ Kg, float* __restrict__ Vg, int c0)
{
    const int nbl = blockIdx.x;
    const int nb  = c0 + nbl;
    const int n   = nb >> 3, h = nb & 7;
    const int tid = threadIdx.x;

    float xr[HD];
    {
        const float4* xp = (const float4*)(x + ((size_t)n*SEQT + tid)*FEATD + h*HD);
        #pragma unroll
        for (int q4 = 0; q4 < 8; ++q4) {
            float4 v = xp[q4];
            xr[q4*4+0] = v.x; xr[q4*4+1] = v.y; xr[q4*4+2] = v.z; xr[q4*4+3] = v.w;
        }
    }
    float ko[HD], vo[HD];
    #pragma unroll
    for (int d = 0; d < HD; ++d) {
        float sk = 0.f, sv = 0.f;
        #pragma unroll
        for (int e = 0; e < HD; ++e) {
            sk += xr[e] * wk[d*HD + e];
            sv += xr[e] * wv[d*HD + e];
        }
        ko[d] = sk; vo[d] = sv;
    }
    float* kp = Kg + (size_t)nbl*8192 + (size_t)tid*HD;
    float* vp = Vg + (size_t)nbl*8192 + (size_t)tid*HD;
    #pragma unroll
    for (int q4 = 0; q4 < 8; ++q4) {
        *(float4*)(kp + q4*4) = make_float4(ko[q4*4+0], ko[q4*4+1], ko[q4*4+2], ko[q4*4+3]);
        *(float4*)(vp + q4*4) = make_float4(vo[q4*4+0], vo[q4*4+1], vo[q4*4+2], vo[q4*4+3]);
    }
}

// ---------------------------------------------------------------------------
// Attention core, LDS-free: Q in registers, K/V rows read as wave-uniform
// global float4 loads (one line per instruction; no LDS broadcast pipe).
// Math order identical to verified R2-R16. Output T-major CB8 bf16.
// ---------------------------------------------------------------------------
__global__ __launch_bounds__(256) void k_attn2(
    const float* __restrict__ x,  const float* __restrict__ wq,
    const float* __restrict__ Kg, const float* __restrict__ Vg,
    u16* __restrict__ attnH, int c0)
{
    const int nbl = blockIdx.x;
    const int nb  = c0 + nbl;
    const int n   = nb >> 3, h = nb & 7;
    const int tid = threadIdx.x;

    float qv[HD];
    {
        float xr[HD];
        const float4* xp = (const float4*)(x + ((size_t)n*SEQT + tid)*FEATD + h*HD);
        #pragma unroll
        for (int q4 = 0; q4 < 8; ++q4) {
            float4 v = xp[q4];
            xr[q4*4+0] = v.x; xr[q4*4+1] = v.y; xr[q4*4+2] = v.z; xr[q4*4+3] = v.w;
        }
        #pragma unroll
        for (int d = 0; d < HD; ++d) {
            float s = 0.f;
            #pragma unroll
            for (int e = 0; e < HD; ++e) s += xr[e] * wq[d*HD + e];
            qv[d] = s * 0.0625f;
        }
    }

    float o[HD];
    #pragma unroll
    for (int d = 0; d < HD; ++d) o[d] = 0.f;
    float m = -1e30f, ssum = 0.f;

    const float* Kb = Kg + (size_t)nbl*8192;
    const float* Vb = Vg + (size_t)nbl*8192;

    for (int j = 0; j < SEQT; ++j) {
        const float4* kp = (const float4*)(Kb + j*HD);
        float e = 0.f;
        #pragma unroll
        for (int dq = 0; dq < 8; ++dq) {
            float4 kq = kp[dq];
            e += qv[dq*4+0]*kq.x + qv[dq*4+1]*kq.y
               + qv[dq*4+2]*kq.z + qv[dq*4+3]*kq.w;
        }
        if (e > m) {
            float sc = __expf(m - e);
            ssum *= sc;
            #pragma unroll
            for (int d = 0; d < HD; ++d) o[d] *= sc;
            m = e;
        }
        float p = __expf(e - m);
        ssum += p;
        const float4* vp = (const float4*)(Vb + j*HD);
        #pragma unroll
        for (int dq = 0; dq < 8; ++dq) {
            float4 vq = vp[dq];
            o[dq*4+0] += p * vq.x; o[dq*4+1] += p * vq.y;
            o[dq*4+2] += p * vq.z; o[dq*4+3] += p * vq.w;
        }
    }

    const float inv = 1.f / ssum;
    #pragma unroll
    for (int dq = 0; dq < 8; ++dq) {
        ushort4 vh;
        vh.x = bf16rn(o[dq*4+0]*inv);
        vh.y = bf16rn(o[dq*4+1]*inv);
        vh.z = bf16rn(o[dq*4+2]*inv);
        vh.w = bf16rn(o[dq*4+3]*inv);
        const size_t a = (size_t)tid*65536
                       + (size_t)(h*4 + (dq >> 1))*2048
                       + (size_t)n*8 + (dq & 1)*4;
        *(ushort4*)(attnH + a) = vh;
    }
}

// ---------------------------------------------------------------------------
// Wc = w_hid @ w_fc; bc = w_hid @ b_fc + b_hid (verified R11-R16)
// ---------------------------------------------------------------------------
__global__ __launch_bounds__(256) void k_wcomb(
    const float* __restrict__ w_fc,  const float* __restrict__ b_fc,
    const float* __restrict__ w_hid, const float* __restrict__ b_hid,
    float* __restrict__ Wc, float* __restrict__ bc)
{
    __shared__ float wr[8][256];
    const int i0 = blockIdx.x * 8, tid = threadIdx.x;
    for (int e = tid; e < 8*256; e += 256)
        wr[e >> 8][e & 255] = w_hid[(size_t)(i0 + (e >> 8))*FEATD + (e & 255)];
    __syncthreads();
    const int j = tid;
    float acc[8] = {};
    for (int k = 0; k < FEATD; ++k) {
        const float wf = w_fc[(size_t)k*FEATD + j];
        #pragma unroll
        for (int i = 0; i < 8; ++i) acc[i] += wr[i][k] * wf;
    }
    #pragma unroll
    for (int i = 0; i < 8; ++i) Wc[(size_t)(i0 + i)*FEATD + j] = acc[i];
    if (tid < 8) {
        const int i = i0 + tid;
        float t = b_hid[i];
        for (int k = 0; k < FEATD; ++k) t += wr[tid][k] * b_fc[k];
        bc[i] = t;
    }
}

// ---------------------------------------------------------------------------
// Wx0 = W_ih[0] @ Wc; bx0 = W_ih[0] @ bc + b_ih[0] + b_hh[0] (verified)
// ---------------------------------------------------------------------------
__global__ __launch_bounds__(256) void k_wx0(
    const float* __restrict__ w_ih, const float* __restrict__ Wc,
    const float* __restrict__ bc,   const float* __restrict__ b_ih,
    const float* __restrict__ b_hh,
    float* __restrict__ Wx0, float* __restrict__ bx0)
{
    __shared__ float wr[8][512];
    const int i0 = blockIdx.x * 8, tid = threadIdx.x;
    for (int e = tid; e < 8*512; e += 256)
        wr[e >> 9][e & 511] = w_ih[(size_t)(i0 + (e >> 9))*HID + (e & 511)];
    __syncthreads();
    const int j = tid;
    float acc[8] = {};
    for (int k = 0; k < HID; ++k) {
        const float wc = Wc[(size_t)k*FEATD + j];
        #pragma unroll
        for (int i = 0; i < 8; ++i) acc[i] += wr[i][k] * wc;
    }
    #pragma unroll
    for (int i = 0; i < 8; ++i) Wx0[(size_t)(i0 + i)*FEATD + j] = acc[i];
    if (tid < 8) {
        const int i = i0 + tid;
        float t = b_ih[i] + b_hh[i];
        for (int k = 0; k < HID; ++k) t += wr[tid][k] * bc[k];
        bx0[i] = t;
    }
}

// ---------------------------------------------------------------------------
// Group barrier pieces + cross-group wait (verified R15/R16).
// ---------------------------------------------------------------------------
__device__ __forceinline__ void bar_arrive(int* gflags, int gidx, int step)
{
    asm volatile("s_waitcnt vmcnt(0)" ::: "memory");   // drain sc1 stores
    __syncthreads();
    if (threadIdx.x == 0)
        __hip_atomic_store(&gflags[gidx], step,
                           __ATOMIC_RELAXED, __HIP_MEMORY_SCOPE_AGENT);
}
__device__ __forceinline__ void bar_aggregate(int* gflags, int* ep, int step)
{
    if (threadIdx.x < 64) {
        const int base = (int)threadIdx.x * 2;
        for (;;) {
            int a = __hip_atomic_load(&gflags[base+0], __ATOMIC_RELAXED, __HIP_MEMORY_SCOPE_AGENT);
            int b = __hip_atomic_load(&gflags[base+1], __ATOMIC_RELAXED, __HIP_MEMORY_SCOPE_AGENT);
            if (__all(a >= step && b >= step)) break;
            __builtin_amdgcn_s_sleep(2);
        }
        if (threadIdx.x == 0)
            __hip_atomic_store(ep, step,
                               __ATOMIC_RELAXED, __HIP_MEMORY_SCOPE_AGENT);
    }
}
__device__ __forceinline__ void bar_wait(int* ep, int step)
{
    if (threadIdx.x == 0) {
        while (__hip_atomic_load(ep, __ATOMIC_RELAXED, __HIP_MEMORY_SCOPE_AGENT) < step)
            __builtin_amdgcn_s_sleep(2);
        __builtin_amdgcn_fence(__ATOMIC_ACQUIRE, "agent");
    }
    __syncthreads();
}
__device__ __forceinline__ void wait_ep(int* ep, int val)
{
    if (threadIdx.x == 0) {
        while (__hip_atomic_load(ep, __ATOMIC_RELAXED, __HIP_MEMORY_SCOPE_AGENT) < val)
            __builtin_amdgcn_s_sleep(2);
        __builtin_amdgcn_fence(__ATOMIC_ACQUIRE, "agent");
    }
    __syncthreads();
}

// ---------------------------------------------------------------------------
struct Geo {
    const u16* wlh; const u16* wll;   // LDS weights, fragment-major (hi+lo)
    float* Cb;                        // LDS gate bounce [128][33]
    u16* hb;                          // LDS h-store bounce [128][8]
    int tid;
    int rowg, aq, bbase;
    int Mtile, col_local;
    int erow, hcl;
    int cg, mg;
    const float* bsum;
};

// Partial GEMM, 2-term split: acc += ah*(wh + wl). A = single bf16 plane.
// (verified R16)
template<int NT>
__device__ __forceinline__ void do_gemm(
    const Geo& G, const u16* __restrict__ sH, int koff, f32x4& acc)
{
    uint4 pfH[DEPTH];
    auto ld = [&](int d, int s) {
        const size_t a = ((size_t)(s*4 + G.aq) << 11) + (size_t)G.rowg * 8;
        pfH[d] = *(const uint4*)(sH + a);
    };
    constexpr int PR = (DEPTH < NT) ? DEPTH : NT;
    #pragma unroll
    for (int d = 0; d < PR; ++d) ld(d, d);
    #pragma unroll
    for (int s = 0; s < NT; ++s) {
        U8 ua;
        ua.u4 = pfH[s % DEPTH];
        if (s + DEPTH < NT) ld(s % DEPTH, s + DEPTH);
        const short8 bh = *(const short8*)(G.wlh + G.bbase + (koff + s)*512);
        const short8 bl = *(const short8*)(G.wll + G.bbase + (koff + s)*512);
        acc = __builtin_amdgcn_mfma_f32_16x16x32_bf16(ua.s8, bh, acc, 0,0,0);
        acc = __builtin_amdgcn_mfma_f32_16x16x32_bf16(ua.s8, bl, acc, 0,0,0);
    }
}

// Epilogue (verified R16): Cb -> gates -> hb -> 128 x 16B sc1 stores.
__device__ __forceinline__ void epi(
    const Geo& G, const f32x4& acc, float& cr, u16* __restrict__ dH)
{
    {
        const int crow = G.Mtile*16 + G.aq*4;
        #pragma unroll
        for (int r = 0; r < 4; ++r)
            G.Cb[(crow + r)*33 + G.col_local] = acc[r];
    }
    __syncthreads();
    {
        float g4[4];
        #pragma unroll
        for (int g = 0; g < 4; ++g) g4[g] = G.Cb[G.erow*33 + g*8 + G.hcl] + G.bsum[g];
        const float gi = sigm(g4[0]), gf = sigm(g4[1]);
        const float gg = tanhfast(g4[2]), go = sigm(g4[3]);
        cr = gf*cr + gi*gg;
        const float h = go * tanhfast(cr);
        G.hb[G.erow*8 + G.hcl] = bf16rn(h);
    }
    __syncthreads();
    if (G.tid < 128) {
        const int row = G.tid;
        const u32x4 v = *(const u32x4*)&G.hb[row*8];
        st16_dev(dH + ((size_t)G.cg << 11) + (size_t)(G.mg*128 + row)*8, v);
    }
}

// ---------------------------------------------------------------------------
// Persistent split-barrier LSTM (verified R15/R16), single-plane A.
// ---------------------------------------------------------------------------
__global__ __launch_bounds__(THR, 1) void k_lstm(
    const u16* __restrict__ attnH,
    const float* __restrict__ Wx0, const float* __restrict__ bx0,
    u16* __restrict__ h0h, u16* __restrict__ h1h,
    const float* __restrict__ w_ih, const float* __restrict__ w_hh,
    const float* __restrict__ b_ih, const float* __restrict__ b_hh,
    const float* __restrict__ w_out, const float* __restrict__ b_out,
    float* __restrict__ out, int* __restrict__ fl)
{
    extern __shared__ char smem[];
    int* l1flags = fl;
    int* l0flags = fl + 128;
    int* l1ep    = fl + 256;
    int* l0ep    = fl + 320;

    const int tid  = threadIdx.x;
    const int bx   = blockIdx.x;
    const bool lay1 = (bx < 128);
    const int idx  = lay1 ? bx : bx - 128;
    const int cg   = idx >> 1;
    const int mg   = idx & 1;
    const int KW   = lay1 ? 1024 : 768;
    const int NS   = KW >> 5;

    u16*   wlh = (u16*)smem;
    u16*   wll = wlh + 2*NS*512;
    float* Cb  = (float*)(smem + 132096);
    u16*   hb  = (u16*)(smem + 148992);

    const int wid = tid >> 6, l = tid & 63;
    const int Mtile = wid & 7, Ntile = wid >> 3;
    const int lr = l & 15, aq = l >> 4;

    Geo G;
    G.wlh = wlh; G.wll = wll; G.Cb = Cb; G.hb = hb; G.tid = tid;
    G.rowg = mg*128 + Mtile*16 + lr;
    G.aq = aq;
    G.Mtile = Mtile;
    G.col_local = Ntile*16 + lr;
    G.bbase = Ntile*NS*512 + l*8;
    G.erow = tid & 127; G.hcl = tid >> 7;
    G.cg = cg; G.mg = mg;

    // ---- stage weights (fragment-major split bf16, verified R10-R16)
    for (int c = 0; c < 32; ++c) {
        const int grow = (c >> 3)*HID + cg*8 + (c & 7);
        const float* src0; const float* src1; int klen0;
        if (lay1) {
            src0 = w_ih + (size_t)GATES*HID + (size_t)grow*HID; klen0 = 512;
            src1 = w_hh + (size_t)GATES*HID + (size_t)grow*HID;
        } else {
            src0 = Wx0 + (size_t)grow*FEATD;                    klen0 = 256;
            src1 = w_hh + (size_t)grow*HID;
        }
        const int fb = (c >> 4)*NS*512 + (c & 15)*8;
        for (int k = tid; k < KW; k += THR) {
            float f = (k < klen0) ? src0[k] : src1[k - klen0];
            u16 hi = bf16rn(f);
            const int fidx = fb + (k >> 5)*512 + (((k >> 3) & 3) << 7) + (k & 7);
            wlh[fidx] = hi;
            wll[fidx] = bf16rn(f - bf2f(hi));
        }
    }

    float bsum[4];
    #pragma unroll
    for (int g = 0; g < 4; ++g) {
        const int gidx = g*HID + cg*8 + G.hcl;
        bsum[g] = lay1 ? (b_ih[GATES + gidx] + b_hh[GATES + gidx]) : bx0[gidx];
    }
    G.bsum = bsum;
    float cr = 0.f;
    __syncthreads();

    auto proj = [&](const u16* hH, int tout) {
        if (tid < 256) {
            const int r = tid >> 7, j = (tid >> 4) & 7, ks = tid & 15;
            const int n = 2*idx + r;
            float s = 0.f;
            #pragma unroll
            for (int kk = 0; kk < 32; ++kk) {
                const int k = ks*32 + kk;
                const size_t a = (size_t)(k >> 3)*2048 + (size_t)n*8 + (k & 7);
                float hv = bf2f(hH[a]);
                hv = hv > 0.f ? hv : 0.f;
                s += hv * w_out[(size_t)j*HID + k];
            }
            s += __shfl_xor(s, 1); s += __shfl_xor(s, 2);
            s += __shfl_xor(s, 4); s += __shfl_xor(s, 8);
            if (ks == 0)
                out[(size_t)n*(TOUT*NHEADS) + (size_t)tout*NHEADS + j] = s + b_out[j];
        }
    };

    f32x4 acc = {0.f, 0.f, 0.f, 0.f};

    if (lay1) {
        // ================= LAYER-1 group =================
        wait_ep(l0ep, 1);
        do_gemm<16>(G, h0h, 0, acc);                       // P(0) = Wih1*h0(0)
        for (int t = 0; t <= 254; ++t) {
            if (t >= 1)
                do_gemm<16>(G, h1h + (size_t)((t-1)&3)*BH, 16, acc);
            epi(G, acc, cr, h1h + (size_t)(t&3)*BH);
            bar_arrive(l1flags, idx, t + 1);
            if (bx == 0) bar_aggregate(l1flags, l1ep, t + 1);
            acc = (f32x4){0.f, 0.f, 0.f, 0.f};
            if (t < 254) {                                  // overlap: P(t+1)
                wait_ep(l0ep, t + 2);
                do_gemm<16>(G, h0h + (size_t)((t+1)&3)*BH, 0, acc);
            }
            bar_wait(l1ep, t + 1);
        }
    } else {
        // ================= LAYER-0 group =================
        do_gemm<8>(G, attnH, 0, acc);                       // s=0: Wx0*attn(0)
        epi(G, acc, cr, h0h);
        bar_arrive(l0flags, idx, 1);
        if (bx == 128) bar_aggregate(l0flags, l0ep, 1);
        acc = (f32x4){0.f, 0.f, 0.f, 0.f};
        do_gemm<8>(G, attnH + 65536, 0, acc);               // P(1)
        bar_wait(l0ep, 1);

        for (int s = 1; s <= 254; ++s) {
            if (s >= 2) wait_ep(l1ep, s - 1);               // ring + proj gate
            do_gemm<16>(G, h0h + (size_t)((s-1)&3)*BH, 8, acc);
            epi(G, acc, cr, h0h + (size_t)(s&3)*BH);
            bar_arrive(l0flags, idx, s + 1);
            if (bx == 128) bar_aggregate(l0flags, l0ep, s + 1);
            acc = (f32x4){0.f, 0.f, 0.f, 0.f};
            if (s < 254)                                    // overlap: P(s+1)
                do_gemm<8>(G, attnH + (size_t)(s+1)*65536, 0, acc);
            if (s >= 2)                                     // overlap: proj
                proj(h1h + (size_t)((s-2)&3)*BH, s - 2);
            bar_wait(l0ep, s + 1);
        }
        // tail projections
        wait_ep(l1ep, 255);
        proj(h1h + (size_t)(253&3)*BH, 253);
        proj(h1h + (size_t)(254&3)*BH, 254);
    }
}

// ---------------------------------------------------------------------------
extern "C" void kernel_launch(void* const* d_in, const int* in_sizes, int n_in,
                              void* d_out, int out_size, void* d_ws, size_t ws_size,
                              hipStream_t stream)
{
    (void)in_sizes; (void)n_in; (void)out_size; (void)ws_size;
    const float* x     = (const float*)d_in[0];
    const float* wq    = (const float*)d_in[1];
    const float* wk    = (const float*)d_in[2];
    const float* wv    = (const float*)d_in[3];
    const float* w_fc  = (const float*)d_in[4];
    const float* b_fc  = (const float*)d_in[5];
    const float* w_hid = (const float*)d_in[6];
    const float* b_hid = (const float*)d_in[7];
    const float* w_ih  = (const float*)d_in[8];
    const float* w_hh  = (const float*)d_in[9];
    const float* b_ih  = (const float*)d_in[10];
    const float* b_hh  = (const float*)d_in[11];
    const float* w_out = (const float*)d_in[12];
    const float* b_out = (const float*)d_in[13];

    float* ws = (float*)d_ws;
    size_t off = 0;
    u16* attnH = (u16*)(ws + off); off += (size_t)SEQT*BATCH*FEATD/2;
    float* Wc  = ws + off; off += (size_t)HID*FEATD;
    float* bc  = ws + off; off += HID;
    float* Wx0 = ws + off; off += (size_t)GATES*FEATD;
    float* bx0 = ws + off; off += GATES;
    u16* h0h = (u16*)(ws + off); off += 2*BH;   // 4 slabs of BH halves
    u16* h1h = (u16*)(ws + off); off += 2*BH;
    int* fl  = (int*)(ws + off); off += 512;    // flags + epochs
    float* Kg = ws + off; off += (size_t)ACH*8192;   // 16.8 MB chunk buffers
    float* Vg = ws + off; off += (size_t)ACH*8192;
    // total ~14M floats = ~56 MB

    (void)hipMemsetAsync(fl, 0, 512*sizeof(int), stream);

    for (int c = 0; c < (BATCH*NHEADS)/ACH; ++c) {
        k_qkv  <<<dim3(ACH), dim3(256), 0, stream>>>(x, wk, wv, Kg, Vg, c*ACH);
        k_attn2<<<dim3(ACH), dim3(256), 0, stream>>>(x, wq, Kg, Vg, attnH, c*ACH);
    }
    k_wcomb <<<dim3(64),  dim3(256), 0, stream>>>(w_fc, b_fc, w_hid, b_hid, Wc, bc);
    k_wx0   <<<dim3(256), dim3(256), 0, stream>>>(w_ih, Wc, bc, b_ih, b_hh, Wx0, bx0);

    const int shmem = 132096 + 128*33*4 + 2048;   // weights + Cb + h bounce
    (void)hipFuncSetAttribute(reinterpret_cast<const void*>(k_lstm),
                              hipFuncAttributeMaxDynamicSharedMemorySize, shmem);
    k_lstm <<<dim3(NBLK), dim3(THR), (size_t)shmem, stream>>>(
        attnH, Wx0, bx0, h0h, h1h,
        w_ih, w_hh, b_ih, b_hh, w_out, b_out, (float*)d_out, fl);
}

// Round 18
// 3523.212 us; speedup vs baseline: 5.3375x; 1.1728x over previous
//
#include <hip/hip_runtime.h>
#include <math.h>

// Problem constants
#define BATCH  256
#define SEQT   256
#define FEATD  256
#define NHEADS 8
#define HD     32
#define HID    512
#define GATES  2048
#define BH     (BATCH*HID)       // halves per h plane slab
#define TOUT   (SEQT-1)
#define NBLK   256
#define THR    1024
#define DEPTH  8                 // prefetch depth (slices), hi-plane only
#define ACH    1024              // attention chunk (nb per pass)

typedef __attribute__((ext_vector_type(8))) short short8;
typedef __attribute__((ext_vector_type(4))) float f32x4;
typedef __attribute__((ext_vector_type(4))) unsigned int u32x4;
typedef unsigned short u16;

union U8 { uint4 u4; short8 s8; };

__device__ __forceinline__ float sigm(float x)     { return 1.f / (1.f + __expf(-x)); }
__device__ __forceinline__ float tanhfast(float x) { return 1.f - 2.f / (1.f + __expf(2.f * x)); }

__device__ __forceinline__ u16 bf16rn(float f) {
    union { float f; unsigned u; } v; v.f = f;
    unsigned r = v.u + 0x7fffu + ((v.u >> 16) & 1u);
    return (u16)(r >> 16);
}
__device__ __forceinline__ float bf2f(u16 h) {
    union { float f; unsigned u; } v; v.u = ((unsigned)h) << 16; return v.f;
}
// unpack 8 bf16 (one uint4) -> 8 floats; 1 VALU op per value
__device__ __forceinline__ void unp8(uint4 u, float* f) {
    union { unsigned u; float f; } a;
    a.u = u.x << 16;          f[0] = a.f;
    a.u = u.x & 0xffff0000u;  f[1] = a.f;
    a.u = u.y << 16;          f[2] = a.f;
    a.u = u.y & 0xffff0000u;  f[3] = a.f;
    a.u = u.z << 16;          f[4] = a.f;
    a.u = u.z & 0xffff0000u;  f[5] = a.f;
    a.u = u.w << 16;          f[6] = a.f;
    a.u = u.w & 0xffff0000u;  f[7] = a.f;
}

// Device-scope (sc1) 16B store (verified R14-R17).
__device__ __forceinline__ void st16_dev(void* p, u32x4 v) {
    unsigned long long a = (unsigned long long)p;
    asm volatile("global_store_dwordx4 %0, %1, off sc1"
                 :: "v"(a), "v"(v) : "memory");
}

// ---------------------------------------------------------------------------
// K/V projections for one chunk of (n,h) pairs -> global bf16 rows.
// Dot order identical to the verified R2-R17 staging loop.
// ---------------------------------------------------------------------------
__global__ __launch_bounds__(256) void k_qkv(
    const float* __restrict__ x,
    const float* __restrict__ wk, const float* __restrict__ wv,
    u16* __restrict__ Kg, u16* __restrict__ Vg, int c0)
{
    const int nbl = blockIdx.x;
    const int nb  = c0 + nbl;
    const int n   = nb >> 3, h = nb & 7;
    const int tid = threadIdx.x;

    float xr[HD];
    {
        const float4* xp = (const float4*)(x + ((size_t)n*SEQT + tid)*FEATD + h*HD);
        #pragma unroll
        for (int q4 = 0; q4 < 8; ++q4) {
            float4 v = xp[q4];
            xr[q4*4+0] = v.x; xr[q4*4+1] = v.y; xr[q4*4+2] = v.z; xr[q4*4+3] = v.w;
        }
    }
    float ko[HD], vo[HD];
    #pragma unroll
    for (int d = 0; d < HD; ++d) {
        float sk = 0.f, sv = 0.f;
        #pragma unroll
        for (int e = 0; e < HD; ++e) {
            sk += xr[e] * wk[d*HD + e];
            sv += xr[e] * wv[d*HD + e];
        }
        ko[d] = sk; vo[d] = sv;
    }
    u16* kp = Kg + (size_t)nbl*8192 + (size_t)tid*HD;
    u16* vp = Vg + (size_t)nbl*8192 + (size_t)tid*HD;
    #pragma unroll
    for (int q4 = 0; q4 < 8; ++q4) {
        ushort4 kv, vv;
        kv.x = bf16rn(ko[q4*4+0]); kv.y = bf16rn(ko[q4*4+1]);
        kv.z = bf16rn(ko[q4*4+2]); kv.w = bf16rn(ko[q4*4+3]);
        vv.x = bf16rn(vo[q4*4+0]); vv.y = bf16rn(vo[q4*4+1]);
        vv.z = bf16rn(vo[q4*4+2]); vv.w = bf16rn(vo[q4*4+3]);
        *(ushort4*)(kp + q4*4) = kv;
        *(ushort4*)(vp + q4*4) = vv;
    }
}

// ---------------------------------------------------------------------------
// Attention core, LDS-free (verified structure R17): Q in registers, K/V
// rows read as wave-uniform uint4 loads of bf16 (4 loads/row vs 8).
// Math order identical to R2-R17. Output T-major CB8 bf16.
// ---------------------------------------------------------------------------
__global__ __launch_bounds__(256) void k_attn2(
    const float* __restrict__ x,  const float* __restrict__ wq,
    const u16* __restrict__ Kg, const u16* __restrict__ Vg,
    u16* __restrict__ attnH, int c0)
{
    const int nbl = blockIdx.x;
    const int nb  = c0 + nbl;
    const int n   = nb >> 3, h = nb & 7;
    const int tid = threadIdx.x;

    float qv[HD];
    {
        float xr[HD];
        const float4* xp = (const float4*)(x + ((size_t)n*SEQT + tid)*FEATD + h*HD);
        #pragma unroll
        for (int q4 = 0; q4 < 8; ++q4) {
            float4 v = xp[q4];
            xr[q4*4+0] = v.x; xr[q4*4+1] = v.y; xr[q4*4+2] = v.z; xr[q4*4+3] = v.w;
        }
        #pragma unroll
        for (int d = 0; d < HD; ++d) {
            float s = 0.f;
            #pragma unroll
            for (int e = 0; e < HD; ++e) s += xr[e] * wq[d*HD + e];
            qv[d] = s * 0.0625f;
        }
    }

    float o[HD];
    #pragma unroll
    for (int d = 0; d < HD; ++d) o[d] = 0.f;
    float m = -1e30f, ssum = 0.f;

    const u16* Kb = Kg + (size_t)nbl*8192;
    const u16* Vb = Vg + (size_t)nbl*8192;

    for (int j = 0; j < SEQT; ++j) {
        float kf[HD];
        {
            const uint4* kp = (const uint4*)(Kb + (size_t)j*HD);
            uint4 u0 = kp[0], u1 = kp[1], u2 = kp[2], u3 = kp[3];
            unp8(u0, kf+0); unp8(u1, kf+8); unp8(u2, kf+16); unp8(u3, kf+24);
        }
        float e = 0.f;
        #pragma unroll
        for (int dq = 0; dq < 8; ++dq) {
            e += qv[dq*4+0]*kf[dq*4+0] + qv[dq*4+1]*kf[dq*4+1]
               + qv[dq*4+2]*kf[dq*4+2] + qv[dq*4+3]*kf[dq*4+3];
        }
        if (e > m) {
            float sc = __expf(m - e);
            ssum *= sc;
            #pragma unroll
            for (int d = 0; d < HD; ++d) o[d] *= sc;
            m = e;
        }
        float p = __expf(e - m);
        ssum += p;
        float vf[HD];
        {
            const uint4* vp = (const uint4*)(Vb + (size_t)j*HD);
            uint4 u0 = vp[0], u1 = vp[1], u2 = vp[2], u3 = vp[3];
            unp8(u0, vf+0); unp8(u1, vf+8); unp8(u2, vf+16); unp8(u3, vf+24);
        }
        #pragma unroll
        for (int d = 0; d < HD; ++d) o[d] += p * vf[d];
    }

    const float inv = 1.f / ssum;
    #pragma unroll
    for (int dq = 0; dq < 8; ++dq) {
        ushort4 vh;
        vh.x = bf16rn(o[dq*4+0]*inv);
        vh.y = bf16rn(o[dq*4+1]*inv);
        vh.z = bf16rn(o[dq*4+2]*inv);
        vh.w = bf16rn(o[dq*4+3]*inv);
        const size_t a = (size_t)tid*65536
                       + (size_t)(h*4 + (dq >> 1))*2048
                       + (size_t)n*8 + (dq & 1)*4;
        *(ushort4*)(attnH + a) = vh;
    }
}

// ---------------------------------------------------------------------------
// Wc = w_hid @ w_fc; bc = w_hid @ b_fc + b_hid (verified R11-R17)
// ---------------------------------------------------------------------------
__global__ __launch_bounds__(256) void k_wcomb(
    const float* __restrict__ w_fc,  const float* __restrict__ b_fc,
    const float* __restrict__ w_hid, const float* __restrict__ b_hid,
    float* __restrict__ Wc, float* __restrict__ bc)
{
    __shared__ float wr[8][256];
    const int i0 = blockIdx.x * 8, tid = threadIdx.x;
    for (int e = tid; e < 8*256; e += 256)
        wr[e >> 8][e & 255] = w_hid[(size_t)(i0 + (e >> 8))*FEATD + (e & 255)];
    __syncthreads();
    const int j = tid;
    float acc[8] = {};
    for (int k = 0; k < FEATD; ++k) {
        const float wf = w_fc[(size_t)k*FEATD + j];
        #pragma unroll
        for (int i = 0; i < 8; ++i) acc[i] += wr[i][k] * wf;
    }
    #pragma unroll
    for (int i = 0; i < 8; ++i) Wc[(size_t)(i0 + i)*FEATD + j] = acc[i];
    if (tid < 8) {
        const int i = i0 + tid;
        float t = b_hid[i];
        for (int k = 0; k < FEATD; ++k) t += wr[tid][k] * b_fc[k];
        bc[i] = t;
    }
}

// ---------------------------------------------------------------------------
// Wx0 = W_ih[0] @ Wc; bx0 = W_ih[0] @ bc + b_ih[0] + b_hh[0] (verified)
// ---------------------------------------------------------------------------
__global__ __launch_bounds__(256) void k_wx0(
    const float* __restrict__ w_ih, const float* __restrict__ Wc,
    const float* __restrict__ bc,   const float* __restrict__ b_ih,
    const float* __restrict__ b_hh,
    float* __restrict__ Wx0, float* __restrict__ bx0)
{
    __shared__ float wr[8][512];
    const int i0 = blockIdx.x * 8, tid = threadIdx.x;
    for (int e = tid; e < 8*512; e += 256)
        wr[e >> 9][e & 511] = w_ih[(size_t)(i0 + (e >> 9))*HID + (e & 511)];
    __syncthreads();
    const int j = tid;
    float acc[8] = {};
    for (int k = 0; k < HID; ++k) {
        const float wc = Wc[(size_t)k*FEATD + j];
        #pragma unroll
        for (int i = 0; i < 8; ++i) acc[i] += wr[i][k] * wc;
    }
    #pragma unroll
    for (int i = 0; i < 8; ++i) Wx0[(size_t)(i0 + i)*FEATD + j] = acc[i];
    if (tid < 8) {
        const int i = i0 + tid;
        float t = b_ih[i] + b_hh[i];
        for (int k = 0; k < HID; ++k) t += wr[tid][k] * bc[k];
        bx0[i] = t;
    }
}

// ---------------------------------------------------------------------------
// Group barrier pieces + cross-group wait (verified R15-R17).
// ---------------------------------------------------------------------------
__device__ __forceinline__ void bar_arrive(int* gflags, int gidx, int step)
{
    asm volatile("s_waitcnt vmcnt(0)" ::: "memory");   // drain sc1 stores
    __syncthreads();
    if (threadIdx.x == 0)
        __hip_atomic_store(&gflags[gidx], step,
                           __ATOMIC_RELAXED, __HIP_MEMORY_SCOPE_AGENT);
}
__device__ __forceinline__ void bar_aggregate(int* gflags, int* ep, int step)
{
    if (threadIdx.x < 64) {
        const int base = (int)threadIdx.x * 2;
        for (;;) {
            int a = __hip_atomic_load(&gflags[base+0], __ATOMIC_RELAXED, __HIP_MEMORY_SCOPE_AGENT);
            int b = __hip_atomic_load(&gflags[base+1], __ATOMIC_RELAXED, __HIP_MEMORY_SCOPE_AGENT);
            if (__all(a >= step && b >= step)) break;
            __builtin_amdgcn_s_sleep(2);
        }
        if (threadIdx.x == 0)
            __hip_atomic_store(ep, step,
                               __ATOMIC_RELAXED, __HIP_MEMORY_SCOPE_AGENT);
    }
}
__device__ __forceinline__ void bar_wait(int* ep, int step)
{
    if (threadIdx.x == 0) {
        while (__hip_atomic_load(ep, __ATOMIC_RELAXED, __HIP_MEMORY_SCOPE_AGENT) < step)
            __builtin_amdgcn_s_sleep(2);
        __builtin_amdgcn_fence(__ATOMIC_ACQUIRE, "agent");
    }
    __syncthreads();
}
__device__ __forceinline__ void wait_ep(int* ep, int val)
{
    if (threadIdx.x == 0) {
        while (__hip_atomic_load(ep, __ATOMIC_RELAXED, __HIP_MEMORY_SCOPE_AGENT) < val)
            __builtin_amdgcn_s_sleep(2);
        __builtin_amdgcn_fence(__ATOMIC_ACQUIRE, "agent");
    }
    __syncthreads();
}

// ---------------------------------------------------------------------------
struct Geo {
    const u16* wlh; const u16* wll;   // LDS weights, fragment-major (hi+lo)
    float* Cb;                        // LDS gate bounce [128][33]
    u16* hb;                          // LDS h-store bounce [128][8]
    int tid;
    int rowg, aq, bbase;
    int Mtile, col_local;
    int erow, hcl;
    int cg, mg;
    const float* bsum;
};

// Partial GEMM, 2-term split: acc += ah*(wh + wl). A = single bf16 plane.
// (verified R16/R17)
template<int NT>
__device__ __forceinline__ void do_gemm(
    const Geo& G, const u16* __restrict__ sH, int koff, f32x4& acc)
{
    uint4 pfH[DEPTH];
    auto ld = [&](int d, int s) {
        const size_t a = ((size_t)(s*4 + G.aq) << 11) + (size_t)G.rowg * 8;
        pfH[d] = *(const uint4*)(sH + a);
    };
    constexpr int PR = (DEPTH < NT) ? DEPTH : NT;
    #pragma unroll
    for (int d = 0; d < PR; ++d) ld(d, d);
    #pragma unroll
    for (int s = 0; s < NT; ++s) {
        U8 ua;
        ua.u4 = pfH[s % DEPTH];
        if (s + DEPTH < NT) ld(s % DEPTH, s + DEPTH);
        const short8 bh = *(const short8*)(G.wlh + G.bbase + (koff + s)*512);
        const short8 bl = *(const short8*)(G.wll + G.bbase + (koff + s)*512);
        acc = __builtin_amdgcn_mfma_f32_16x16x32_bf16(ua.s8, bh, acc, 0,0,0);
        acc = __builtin_amdgcn_mfma_f32_16x16x32_bf16(ua.s8, bl, acc, 0,0,0);
    }
}

// Epilogue (verified R16/R17): Cb -> gates -> hb -> 128 x 16B sc1 stores.
__device__ __forceinline__ void epi(
    const Geo& G, const f32x4& acc, float& cr, u16* __restrict__ dH)
{
    {
        const int crow = G.Mtile*16 + G.aq*4;
        #pragma unroll
        for (int r = 0; r < 4; ++r)
            G.Cb[(crow + r)*33 + G.col_local] = acc[r];
    }
    __syncthreads();
    {
        float g4[4];
        #pragma unroll
        for (int g = 0; g < 4; ++g) g4[g] = G.Cb[G.erow*33 + g*8 + G.hcl] + G.bsum[g];
        const float gi = sigm(g4[0]), gf = sigm(g4[1]);
        const float gg = tanhfast(g4[2]), go = sigm(g4[3]);
        cr = gf*cr + gi*gg;
        const float h = go * tanhfast(cr);
        G.hb[G.erow*8 + G.hcl] = bf16rn(h);
    }
    __syncthreads();
    if (G.tid < 128) {
        const int row = G.tid;
        const u32x4 v = *(const u32x4*)&G.hb[row*8];
        st16_dev(dH + ((size_t)G.cg << 11) + (size_t)(G.mg*128 + row)*8, v);
    }
}

// ---------------------------------------------------------------------------
// Persistent split-barrier LSTM (verified R15-R17), single-plane A.
// ---------------------------------------------------------------------------
__global__ __launch_bounds__(THR, 1) void k_lstm(
    const u16* __restrict__ attnH,
    const float* __restrict__ Wx0, const float* __restrict__ bx0,
    u16* __restrict__ h0h, u16* __restrict__ h1h,
    const float* __restrict__ w_ih, const float* __restrict__ w_hh,
    const float* __restrict__ b_ih, const float* __restrict__ b_hh,
    const float* __restrict__ w_out, const float* __restrict__ b_out,
    float* __restrict__ out, int* __restrict__ fl)
{
    extern __shared__ char smem[];
    int* l1flags = fl;
    int* l0flags = fl + 128;
    int* l1ep    = fl + 256;
    int* l0ep    = fl + 320;

    const int tid  = threadIdx.x;
    const int bx   = blockIdx.x;
    const bool lay1 = (bx < 128);
    const int idx  = lay1 ? bx : bx - 128;
    const int cg   = idx >> 1;
    const int mg   = idx & 1;
    const int KW   = lay1 ? 1024 : 768;
    const int NS   = KW >> 5;

    u16*   wlh = (u16*)smem;
    u16*   wll = wlh + 2*NS*512;
    float* Cb  = (float*)(smem + 132096);
    u16*   hb  = (u16*)(smem + 148992);

    const int wid = tid >> 6, l = tid & 63;
    const int Mtile = wid & 7, Ntile = wid >> 3;
    const int lr = l & 15, aq = l >> 4;

    Geo G;
    G.wlh = wlh; G.wll = wll; G.Cb = Cb; G.hb = hb; G.tid = tid;
    G.rowg = mg*128 + Mtile*16 + lr;
    G.aq = aq;
    G.Mtile = Mtile;
    G.col_local = Ntile*16 + lr;
    G.bbase = Ntile*NS*512 + l*8;
    G.erow = tid & 127; G.hcl = tid >> 7;
    G.cg = cg; G.mg = mg;

    // ---- stage weights (fragment-major split bf16, verified R10-R17)
    for (int c = 0; c < 32; ++c) {
        const int grow = (c >> 3)*HID + cg*8 + (c & 7);
        const float* src0; const float* src1; int klen0;
        if (lay1) {
            src0 = w_ih + (size_t)GATES*HID + (size_t)grow*HID; klen0 = 512;
            src1 = w_hh + (size_t)GATES*HID + (size_t)grow*HID;
        } else {
            src0 = Wx0 + (size_t)grow*FEATD;                    klen0 = 256;
            src1 = w_hh + (size_t)grow*HID;
        }
        const int fb = (c >> 4)*NS*512 + (c & 15)*8;
        for (int k = tid; k < KW; k += THR) {
            float f = (k < klen0) ? src0[k] : src1[k - klen0];
            u16 hi = bf16rn(f);
            const int fidx = fb + (k >> 5)*512 + (((k >> 3) & 3) << 7) + (k & 7);
            wlh[fidx] = hi;
            wll[fidx] = bf16rn(f - bf2f(hi));
        }
    }

    float bsum[4];
    #pragma unroll
    for (int g = 0; g < 4; ++g) {
        const int gidx = g*HID + cg*8 + G.hcl;
        bsum[g] = lay1 ? (b_ih[GATES + gidx] + b_hh[GATES + gidx]) : bx0[gidx];
    }
    G.bsum = bsum;
    float cr = 0.f;
    __syncthreads();

    auto proj = [&](const u16* hH, int tout) {
        if (tid < 256) {
            const int r = tid >> 7, j = (tid >> 4) & 7, ks = tid & 15;
            const int n = 2*idx + r;
            float s = 0.f;
            #pragma unroll
            for (int kk = 0; kk < 32; ++kk) {
                const int k = ks*32 + kk;
                const size_t a = (size_t)(k >> 3)*2048 + (size_t)n*8 + (k & 7);
                float hv = bf2f(hH[a]);
                hv = hv > 0.f ? hv : 0.f;
                s += hv * w_out[(size_t)j*HID + k];
            }
            s += __shfl_xor(s, 1); s += __shfl_xor(s, 2);
            s += __shfl_xor(s, 4); s += __shfl_xor(s, 8);
            if (ks == 0)
                out[(size_t)n*(TOUT*NHEADS) + (size_t)tout*NHEADS + j] = s + b_out[j];
        }
    };

    f32x4 acc = {0.f, 0.f, 0.f, 0.f};

    if (lay1) {
        // ================= LAYER-1 group =================
        wait_ep(l0ep, 1);
        do_gemm<16>(G, h0h, 0, acc);                       // P(0) = Wih1*h0(0)
        for (int t = 0; t <= 254; ++t) {
            if (t >= 1)
                do_gemm<16>(G, h1h + (size_t)((t-1)&3)*BH, 16, acc);
            epi(G, acc, cr, h1h + (size_t)(t&3)*BH);
            bar_arrive(l1flags, idx, t + 1);
            if (bx == 0) bar_aggregate(l1flags, l1ep, t + 1);
            acc = (f32x4){0.f, 0.f, 0.f, 0.f};
            if (t < 254) {                                  // overlap: P(t+1)
                wait_ep(l0ep, t + 2);
                do_gemm<16>(G, h0h + (size_t)((t+1)&3)*BH, 0, acc);
            }
            bar_wait(l1ep, t + 1);
        }
    } else {
        // ================= LAYER-0 group =================
        do_gemm<8>(G, attnH, 0, acc);                       // s=0: Wx0*attn(0)
        epi(G, acc, cr, h0h);
        bar_arrive(l0flags, idx, 1);
        if (bx == 128) bar_aggregate(l0flags, l0ep, 1);
        acc = (f32x4){0.f, 0.f, 0.f, 0.f};
        do_gemm<8>(G, attnH + 65536, 0, acc);               // P(1)
        bar_wait(l0ep, 1);

        for (int s = 1; s <= 254; ++s) {
            if (s >= 2) wait_ep(l1ep, s - 1);               // ring + proj gate
            do_gemm<16>(G, h0h + (size_t)((s-1)&3)*BH, 8, acc);
            epi(G, acc, cr, h0h + (size_t)(s&3)*BH);
            bar_arrive(l0flags, idx, s + 1);
            if (bx == 128) bar_aggregate(l0flags, l0ep, s + 1);
            acc = (f32x4){0.f, 0.f, 0.f, 0.f};
            if (s < 254)                                    // overlap: P(s+1)
                do_gemm<8>(G, attnH + (size_t)(s+1)*65536, 0, acc);
            if (s >= 2)                                     // overlap: proj
                proj(h1h + (size_t)((s-2)&3)*BH, s - 2);
            bar_wait(l0ep, s + 1);
        }
        // tail projections
        wait_ep(l1ep, 255);
        proj(h1h + (size_t)(253&3)*BH, 253);
        proj(h1h + (size_t)(254&3)*BH, 254);
    }
}

// ---------------------------------------------------------------------------
extern "C" void kernel_launch(void* const* d_in, const int* in_sizes, int n_in,
                              void* d_out, int out_size, void* d_ws, size_t ws_size,
                              hipStream_t stream)
{
    (void)in_sizes; (void)n_in; (void)out_size; (void)ws_size;
    const float* x     = (const float*)d_in[0];
    const float* wq    = (const float*)d_in[1];
    const float* wk    = (const float*)d_in[2];
    const float* wv    = (const float*)d_in[3];
    const float* w_fc  = (const float*)d_in[4];
    const float* b_fc  = (const float*)d_in[5];
    const float* w_hid = (const float*)d_in[6];
    const float* b_hid = (const float*)d_in[7];
    const float* w_ih  = (const float*)d_in[8];
    const float* w_hh  = (const float*)d_in[9];
    const float* b_ih  = (const float*)d_in[10];
    const float* b_hh  = (const float*)d_in[11];
    const float* w_out = (const float*)d_in[12];
    const float* b_out = (const float*)d_in[13];

    float* ws = (float*)d_ws;
    size_t off = 0;
    u16* attnH = (u16*)(ws + off); off += (size_t)SEQT*BATCH*FEATD/2;
    float* Wc  = ws + off; off += (size_t)HID*FEATD;
    float* bc  = ws + off; off += HID;
    float* Wx0 = ws + off; off += (size_t)GATES*FEATD;
    float* bx0 = ws + off; off += GATES;
    u16* h0h = (u16*)(ws + off); off += 2*BH;   // 4 slabs of BH halves
    u16* h1h = (u16*)(ws + off); off += 2*BH;
    int* fl  = (int*)(ws + off); off += 512;    // flags + epochs
    u16* Kg  = (u16*)(ws + off); off += (size_t)ACH*8192/2;  // bf16 chunks
    u16* Vg  = (u16*)(ws + off); off += (size_t)ACH*8192/2;
    // total ~17.8M floats = ~71 MB (< 89 MB proven in R7)

    (void)hipMemsetAsync(fl, 0, 512*sizeof(int), stream);

    for (int c = 0; c < (BATCH*NHEADS)/ACH; ++c) {
        k_qkv  <<<dim3(ACH), dim3(256), 0, stream>>>(x, wk, wv, Kg, Vg, c*ACH);
        k_attn2<<<dim3(ACH), dim3(256), 0, stream>>>(x, wq, Kg, Vg, attnH, c*ACH);
    }
    k_wcomb <<<dim3(64),  dim3(256), 0, stream>>>(w_fc, b_fc, w_hid, b_hid, Wc, bc);
    k_wx0   <<<dim3(256), dim3(256), 0, stream>>>(w_ih, Wc, bc, b_ih, b_hh, Wx0, bx0);

    const int shmem = 132096 + 128*33*4 + 2048;   // weights + Cb + h bounce
    (void)hipFuncSetAttribute(reinterpret_cast<const void*>(k_lstm),
                              hipFuncAttributeMaxDynamicSharedMemorySize, shmem);
    k_lstm <<<dim3(NBLK), dim3(THR), (size_t)shmem, stream>>>(
        attnH, Wx0, bx0, h0h, h1h,
        w_ih, w_hh, b_ih, b_hh, w_out, b_out, (float*)d_out, fl);
}